// Round 9
// baseline (510.207 us; speedup 1.0000x reference)
//
#include <hip/hip_runtime.h>
#include <math.h>

#define NN 100000
#define NPAD 100096
#define NT128 782     // NPAD / 128 (gru blocks)
#define NE 800000
#define DD 128
#define SLOTS 40      // fixed-slot edge table; Poisson(8) in-degree, P(>=40) ~ 6e-16

#define EMB_BLKS 6256     // NPAD*16/256
#define PLACE_BLKS 3125   // NE/256
#define CPREP_BLKS 96
#define WPREP_BLKS 192
// first 2*PLACE_BLKS blocks alternate place/embed so both run concurrently on
// every CU (grid-order dispatch had previously serialized them)
#define MEGA_BLKS (2 * PLACE_BLKS + (EMB_BLKS - PLACE_BLKS) + CPREP_BLKS + WPREP_BLKS + 7 + 1)

typedef __attribute__((ext_vector_type(8))) short short8;
typedef __attribute__((ext_vector_type(4))) float floatx4;
typedef __attribute__((ext_vector_type(4))) float fx4;
typedef unsigned short ush_t;
typedef __attribute__((ext_vector_type(8))) unsigned short ushort8_t;

__device__ __forceinline__ ush_t f2bf(float f) {
    unsigned u = __float_as_uint(f);
    return (ush_t)((u + 0x7fffu + ((u >> 16) & 1u)) >> 16);
}
__device__ __forceinline__ float bf2f(ush_t h) {
    return __uint_as_float((unsigned)h << 16);
}
__device__ __forceinline__ float sigf(float x) {
    return __builtin_amdgcn_rcpf(1.0f + __expf(-x));
}
__device__ __forceinline__ float tanhf_fast(float x) {
    x = fminf(fmaxf(x, -20.0f), 20.0f);
    float e = __expf(2.0f * x);
    return 1.0f - 2.0f * __builtin_amdgcn_rcpf(e + 1.0f);
}

// ---------------------------------------------------------------- mega-prep:
// place (single-pass fixed-slot edge table) ∥ embed ∥ cprep ∥ wprep ∥ rowmean ∥ accz.
__global__ __launch_bounds__(256) void mega_kernel(
        const int* __restrict__ src, const int* __restrict__ dst,
        const int* __restrict__ et, unsigned* __restrict__ csr,
        int* __restrict__ fill,
        const int* __restrict__ ids, const float* __restrict__ tab, ush_t* __restrict__ x,
        const float* __restrict__ Wih, const float* __restrict__ G,
        const float* __restrict__ Whh, ush_t* __restrict__ WB,
        const float* __restrict__ etab, float* __restrict__ rm,
        float* __restrict__ accz) {
    __shared__ float sW[16 * 128];
    int b = blockIdx.x;
    int t = threadIdx.x;
    int role;          // 0 = place, 1 = embed, 2 = rest
    int idx;
    if (b < 2 * PLACE_BLKS) {
        role = b & 1;
        idx = b >> 1;
    } else {
        int r = b - 2 * PLACE_BLKS;
        if (r < EMB_BLKS - PLACE_BLKS) { role = 1; idx = PLACE_BLKS + r; }
        else { role = 2; idx = r - (EMB_BLKS - PLACE_BLKS); }
    }
    if (role == 0) {
        // ---- single-pass placement: one atomic + one scattered 4B store per edge
        int e = idx * 256 + t;
        if (e < NE) {
            int d  = __builtin_nontemporal_load(dst + e);
            int s  = __builtin_nontemporal_load(src + e);
            int ty = __builtin_nontemporal_load(et + e);
            int pos = atomicAdd(&fill[d], 1);
            if (pos < SLOTS)
                csr[(size_t)d * SLOTS + pos] = (unsigned)s | ((unsigned)(ty - 1) << 17);
        }
        return;
    }
    if (role == 1) {
        // ---- embedding gather -> bf16 row-major
        int tid = idx * 256 + t;
        int n = tid >> 4, c = tid & 15;
        if (n >= NPAD) return;
        ushort8_t h;
        if (n < NN) {
            int id = __builtin_nontemporal_load(ids + n);
            const fx4* srcp = (const fx4*)(tab + (size_t)(id + 1) * DD + c * 8);
            fx4 v0 = __builtin_nontemporal_load(srcp);
            fx4 v1 = __builtin_nontemporal_load(srcp + 1);
            h[0] = f2bf(v0[0]); h[1] = f2bf(v0[1]); h[2] = f2bf(v0[2]); h[3] = f2bf(v0[3]);
            h[4] = f2bf(v1[0]); h[5] = f2bf(v1[1]); h[6] = f2bf(v1[2]); h[7] = f2bf(v1[3]);
        } else {
            #pragma unroll
            for (int e2 = 0; e2 < 8; ++e2) h[e2] = 0;
        }
        __builtin_nontemporal_store(h, (ushort8_t*)(x + (size_t)n * DD + c * 8));
        return;
    }
    int b2 = idx;
    if (b2 < CPREP_BLKS) {
        // ---- combined weights: C[l,g] = W_l @ Wih_g^T
        int mat = b2 >> 3, rg = b2 & 7;
        int l = mat / 3, g = mat % 3;
        int k0 = rg * 16;
        #pragma unroll
        for (int it = 0; it < 8; ++it) {
            int idx2 = it * 256 + t;
            sW[idx2] = G[(size_t)l * 16384 + (size_t)(k0 + (idx2 >> 7)) * 128 + (idx2 & 127)];
        }
        __syncthreads();
        int col = t & 127, kh = t >> 7;
        float acc[8];
        #pragma unroll
        for (int e2 = 0; e2 < 8; ++e2) acc[e2] = 0.f;
        const float* wr = Wih + (size_t)(g * 128 + col) * 128;
        for (int j = 0; j < 128; ++j) {
            float wv = wr[j];
            #pragma unroll
            for (int e2 = 0; e2 < 8; ++e2) acc[e2] += sW[(kh * 8 + e2) * 128 + j] * wv;
        }
        int M = 3 + l * 3 + g;
        #pragma unroll
        for (int e2 = 0; e2 < 8; ++e2) {
            int k = k0 + kh * 8 + e2;
            int chunk = k >> 5, klo = k & 31;
            int inoff = ((col >> 4) * 4 + (klo >> 3)) * 128 + (col & 15) * 8 + (klo & 7);
            WB[(size_t)(M * 4 + chunk) * 4096 + inoff] = f2bf(acc[e2]);
        }
        return;
    }
    b2 -= CPREP_BLKS;
    if (b2 < WPREP_BLKS) {
        // ---- Whh gates -> WB mats 0..2
        int idx2 = b2 * 256 + t;
        int mat = idx2 >> 14;
        int rem = idx2 & 16383;
        int col = rem & 127, kk = rem >> 7;
        float w = Whh[((size_t)mat * 128 + col) * 128 + kk];
        int chunk = kk >> 5, klo = kk & 31;
        int inoff = ((col >> 4) * 4 + (klo >> 3)) * 128 + (col & 15) * 8 + (klo & 7);
        WB[(size_t)(mat * 4 + chunk) * 4096 + inoff] = f2bf(w);
        return;
    }
    b2 -= WPREP_BLKS;
    if (b2 < 7) {
        // ---- row means of edge-type table (7 blocks)
        int r = b2;
        float v = (t < 128) ? etab[r * DD + t] : 0.f;
        #pragma unroll
        for (int o = 32; o > 0; o >>= 1) v += __shfl_xor(v, o);
        if ((t & 63) == 0) sW[t >> 6] = v;
        __syncthreads();
        if (t == 0) rm[r] = (sW[0] + sW[1]) * (1.0f / DD);
        return;
    }
    // ---- zero pooling accumulators (1 block)
    for (int i = t; i < 64 * 128 + 64; i += 256) accz[i] = 0.f;
}

// ---------------------------------------------------------------- slot-table gather: g = sum rm[et]*x[src]
// 16 lanes per node, 16-B row loads; unroll 8/4/1 for deeper MLP on the
// typical-degree (Poisson(8)) rows.
__global__ __launch_bounds__(512) void agg_kernel(const ush_t* __restrict__ x,
                                                  const int* __restrict__ fill,
                                                  const unsigned* __restrict__ csr,
                                                  const float* __restrict__ rm,
                                                  ush_t* __restrict__ gH) {
    __shared__ float srm[8];
    int t = threadIdx.x;
    if (t < 7) srm[t] = rm[t];
    __syncthreads();
    int grp = t >> 4, c = t & 15;
    int n = blockIdx.x * 32 + grp;
    if (n >= NPAD) return;
    int nout = ((n >> 7) << 14) + ((c >> 2) << 12) + (((n >> 4) & 7) << 9)
             + ((c & 3) << 7) + ((n & 15) << 3);
    if (n >= NN) {
        ushort8_t z;
        #pragma unroll
        for (int k = 0; k < 8; ++k) z[k] = 0;
        *(ushort8_t*)(gH + nout) = z;
        return;
    }
    const ush_t* xc = x + c * 8;
    const unsigned* cp = csr + (size_t)n * SLOTS;
    int cnt = fill[n];
    if (cnt > SLOTS) cnt = SLOTS;
    float acc[8];
    #pragma unroll
    for (int k = 0; k < 8; ++k) acc[k] = 0.f;
    int e = 0;
    for (; e + 7 < cnt; e += 8) {
        unsigned r[8];
        #pragma unroll
        for (int j = 0; j < 8; ++j) r[j] = cp[e + j];
        ushort8_t p[8];
        #pragma unroll
        for (int j = 0; j < 8; ++j)
            p[j] = *(const ushort8_t*)(xc + (size_t)(r[j] & 0x1FFFFu) * DD);
        #pragma unroll
        for (int j = 0; j < 8; ++j) {
            float w = srm[r[j] >> 17];
            #pragma unroll
            for (int k = 0; k < 8; ++k) acc[k] += w * bf2f(p[j][k]);
        }
    }
    for (; e + 3 < cnt; e += 4) {
        unsigned r0 = cp[e], r1 = cp[e + 1], r2 = cp[e + 2], r3 = cp[e + 3];
        float w0 = srm[r0 >> 17], w1 = srm[r1 >> 17];
        float w2 = srm[r2 >> 17], w3 = srm[r3 >> 17];
        ushort8_t p0 = *(const ushort8_t*)(xc + (size_t)(r0 & 0x1FFFFu) * DD);
        ushort8_t p1 = *(const ushort8_t*)(xc + (size_t)(r1 & 0x1FFFFu) * DD);
        ushort8_t p2 = *(const ushort8_t*)(xc + (size_t)(r2 & 0x1FFFFu) * DD);
        ushort8_t p3 = *(const ushort8_t*)(xc + (size_t)(r3 & 0x1FFFFu) * DD);
        #pragma unroll
        for (int k = 0; k < 8; ++k)
            acc[k] += w0 * bf2f(p0[k]) + w1 * bf2f(p1[k])
                    + w2 * bf2f(p2[k]) + w3 * bf2f(p3[k]);
    }
    for (; e < cnt; ++e) {
        unsigned r0 = cp[e];
        float w0 = srm[r0 >> 17];
        ushort8_t p0 = *(const ushort8_t*)(xc + (size_t)(r0 & 0x1FFFFu) * DD);
        #pragma unroll
        for (int k = 0; k < 8; ++k) acc[k] += w0 * bf2f(p0[k]);
    }
    ushort8_t oh;
    #pragma unroll
    for (int k = 0; k < 8; ++k) oh[k] = f2bf(acc[k]);
    *(ushort8_t*)(gH + nout) = oh;
}

// ---------------------------------------------------------------- GRU layer kernel (128-row tiles, 8 waves)
// __launch_bounds__(512,2): 256-VGPR budget. acc = 128 regs (8 row-tiles x 4
// gates) leaves ~100 free regs so the compiler can prefetch WB B-fragments
// several K-steps deep (at (512,4)/128-reg the 64-reg acc left zero headroom
// and every B-load exposed L2 latency). Each B-fragment now feeds 8 MFMAs
// (was 4): WB L2 traffic halves. 128-row tile == one gH frag superblock, so
// sG staging is a single contiguous 32KB copy.
__global__ __launch_bounds__(512, 2) void gru_kernel(const ush_t* __restrict__ xin,
                                                     const ush_t* __restrict__ gH,
                                                     ush_t* __restrict__ xout,
                                                     const ush_t* __restrict__ WB,
                                                     const float* __restrict__ bih,
                                                     const float* __restrict__ bhh,
                                                     int layer, int is_last,
                                                     const float* __restrict__ gw,
                                                     const float* __restrict__ gb,
                                                     float* __restrict__ accum,
                                                     float* __restrict__ den) {
    __shared__ ush_t sX[128 * 136];
    __shared__ ush_t sG[128 * 128];    // frag-plane superblock, linear copy
    __shared__ float pl[128];
    int t = threadIdx.x;
    int tb = blockIdx.x;
    int n0 = tb * 128;
    // --- stage x tile (row-major, padded pitch): 128 rows x 16 segs
    #pragma unroll
    for (int it = 0; it < 4; ++it) {
        int idx = it * 512 + t;          // 2048 chunks of 16B
        int row = idx >> 4, seg = idx & 15;
        ushort8_t v = *(const ushort8_t*)(xin + (size_t)(n0 + row) * DD + seg * 8);
        *(ushort8_t*)(sX + row * 136 + seg * 8) = v;
    }
    // --- stage gH tile: one contiguous 16384-ush superblock
    {
        size_t gsrc = (size_t)tb * 16384;
        #pragma unroll
        for (int it = 0; it < 4; ++it) {
            int o = (it * 512 + t) * 8;
            ushort8_t v = *(const ushort8_t*)(gH + gsrc + o);
            *(ushort8_t*)(sG + o) = v;
        }
    }
    __syncthreads();
    // --- MFMA
    int l = t & 63, w = t >> 6;          // w = 0..7: column tile
    int lg = l >> 4, lc = l & 15;
    floatx4 accR[8], accZ[8], accN[8], accI[8];
    #pragma unroll
    for (int i = 0; i < 8; ++i) {
        accR[i] = (floatx4)0.f; accZ[i] = (floatx4)0.f;
        accN[i] = (floatx4)0.f; accI[i] = (floatx4)0.f;
    }
    int boff = ((w * 4 + lg) * 16 + lc) * 8;
    #pragma unroll
    for (int pass = 0; pass < 2; ++pass) {
        int matbase = pass ? (3 + layer * 3) : 0;
        #pragma unroll
        for (int kc = 0; kc < 4; ++kc) {
            short8 aHf[8];
            if (pass == 0) {
                #pragma unroll
                for (int i = 0; i < 8; ++i)
                    aHf[i] = *(const short8*)(sX + (i * 16 + lc) * 136 + kc * 32 + lg * 8);
            } else {
                #pragma unroll
                for (int i = 0; i < 8; ++i)
                    aHf[i] = *(const short8*)(sG + kc * 4096 + i * 512 + lg * 128 + lc * 8);
            }
            #pragma unroll
            for (int m3 = 0; m3 < 3; ++m3) {
                floatx4* accp = (m3 == 0) ? accR : (m3 == 1) ? accZ : (pass ? accI : accN);
                const ush_t* wb = WB + (size_t)((matbase + m3) * 4 + kc) * 4096;
                short8 bH = *(const short8*)(wb + boff);
                #pragma unroll
                for (int i = 0; i < 8; ++i)
                    accp[i] = __builtin_amdgcn_mfma_f32_16x16x32_bf16(aHf[i], bH, accp[i], 0, 0, 0);
            }
        }
    }
    __syncthreads();   // all sX A-frag reads done before overwrite
    // --- gates + blend, in-place into sX
    {
        int col = w * 16 + lc;
        float bIr = bih[col],       bHr = bhh[col];
        float bIz = bih[128 + col], bHz = bhh[128 + col];
        float bIn = bih[256 + col], bHn = bhh[256 + col];
        #pragma unroll
        for (int i = 0; i < 8; ++i)
            #pragma unroll
            for (int r = 0; r < 4; ++r) {
                int row = i * 16 + lg * 4 + r;
                float v = 0.f;
                if (n0 + row < NN) {
                    float rr = sigf(accR[i][r] + bIr + bHr);
                    float zz = sigf(accZ[i][r] + bIz + bHz);
                    float nn = tanhf_fast(accI[i][r] + bIn + rr * (accN[i][r] + bHn));
                    float h = bf2f(sX[row * 136 + col]);
                    v = (1.0f - zz) * nn + zz * h;
                }
                sX[row * 136 + col] = f2bf(v);
            }
    }
    __syncthreads();
    if (!is_last) {
        // --- coalesced row-major write-out
        #pragma unroll
        for (int it = 0; it < 4; ++it) {
            int idx = it * 512 + t;
            int row = idx >> 4, seg = idx & 15;
            ushort8_t v = *(const ushort8_t*)(sX + row * 136 + seg * 8);
            *(ushort8_t*)(xout + (size_t)(n0 + row) * DD + seg * 8) = v;
        }
    } else {
        // --- fused global-attention pooling (replicated accumulators)
        int row = t >> 2, q = t & 3;      // 4 threads per row, 32 cols each
        float s = 0.f;
        #pragma unroll
        for (int e = 0; e < 32; ++e)
            s += bf2f(sX[row * 136 + q * 32 + e]) * gw[q * 32 + e];
        s += __shfl_xor(s, 1);
        s += __shfl_xor(s, 2);
        if (q == 0)
            pl[row] = (n0 + row < NN) ? __expf(sigf(s + gb[0])) : 0.f;
        __syncthreads();
        int cc = t & 127, qr = t >> 7;    // 4 quarters of 32 rows each
        float acc = 0.f;
        #pragma unroll
        for (int r = 0; r < 32; ++r)
            acc += pl[qr * 32 + r] * bf2f(sX[(qr * 32 + r) * 136 + cc]);
        atomicAdd(&accum[(tb & 63) * 128 + cc], acc);
        if (t < 128) {
            float v = pl[t];
            #pragma unroll
            for (int o = 32; o > 0; o >>= 1) v += __shfl_xor(v, o);
            if ((t & 63) == 0) atomicAdd(&den[tb & 63], v);
        }
    }
}

__global__ void finalize_kernel(const float* __restrict__ accum, const float* __restrict__ den,
                                float* __restrict__ out) {
    __shared__ float dsum;
    int d = threadIdx.x;   // 128
    float s = 0.f;
    for (int rep = 0; rep < 64; ++rep) s += accum[rep * 128 + d];
    if (d == 0) {
        float ds = 0.f;
        for (int rep = 0; rep < 64; ++rep) ds += den[rep];
        dsum = ds;
    }
    __syncthreads();
    out[d] = s / dsum;
}

// ---------------------------------------------------------------- launch
extern "C" void kernel_launch(void* const* d_in, const int* in_sizes, int n_in,
                              void* d_out, int out_size, void* d_ws, size_t ws_size,
                              hipStream_t stream) {
    const int*   node_ids    = (const int*)d_in[0];
    const int*   edges       = (const int*)d_in[1];
    const int*   edge_types  = (const int*)d_in[2];
    const float* embed_table = (const float*)d_in[3];
    const float* edge_tab    = (const float*)d_in[4];
    const float* ggnn_w      = (const float*)d_in[5];
    const float* Wih         = (const float*)d_in[6];
    const float* Whh         = (const float*)d_in[7];
    const float* bih         = (const float*)d_in[8];
    const float* bhh         = (const float*)d_in[9];
    const float* gate_w      = (const float*)d_in[10];
    const float* gate_b      = (const float*)d_in[11];
    float* out = (float*)d_out;

    const size_t PL = (size_t)NPAD * DD;
    ush_t* wsb  = (ush_t*)d_ws;
    ush_t* xA   = wsb;
    ush_t* xB   = xA + PL;
    ush_t* gH   = xB + PL;          // frag plane
    ush_t* WB   = gH + PL;          // 15 mats * 4 chunks * 4096
    unsigned* csr = (unsigned*)(WB + 15 * 4 * 4096);  // NPAD*SLOTS 4B records
    float* accum = (float*)(csr + (size_t)NPAD * SLOTS);  // 64 * 128
    float* den   = accum + 64 * 128;    // 64
    float* rm    = den + 64;            // 7(+1)
    int*   fill  = (int*)(rm + 8);      // N

    const int* src = edges;
    const int* dst = edges + NE;

    // prep: memset fill, then ONE mega kernel (place ∥ embed ∥ cprep ∥ wprep ∥ rowmean ∥ accz)
    hipMemsetAsync(fill, 0, NN * sizeof(int), stream);
    mega_kernel<<<MEGA_BLKS, 256, 0, stream>>>(src, dst, edge_types, csr, fill,
                                               node_ids, embed_table, xA,
                                               Wih, ggnn_w, Whh, WB,
                                               edge_tab, rm, accum);

    // 4 layers: standalone high-occupancy gather + gru
    ush_t* x = xA;
    ush_t* xo = xB;
    for (int layer = 0; layer < 4; ++layer) {
        agg_kernel<<<(NPAD + 31) / 32, 512, 0, stream>>>(x, fill, csr, rm, gH);
        gru_kernel<<<NT128, 512, 0, stream>>>(x, gH, xo, WB, bih, bhh,
                                              layer, layer == 3 ? 1 : 0,
                                              gate_w, gate_b, accum, den);
        ush_t* tmp = x; x = xo; xo = tmp;
    }

    finalize_kernel<<<1, 128, 0, stream>>>(accum, den, out);
}

// Round 10
// 466.210 us; speedup vs baseline: 1.0944x; 1.0944x over previous
//
#include <hip/hip_runtime.h>
#include <math.h>

#define NN 100000
#define NPAD 100096
#define NT64 1564     // NPAD / 64 (gru blocks)
#define NE 800000
#define DD 128
#define SLOTS 40      // fixed-slot edge table; Poisson(8) in-degree, P(>=40) ~ 6e-16

#define EMB_BLKS 6256     // NPAD*16/256
#define PLACE_BLKS 3125   // NE/256
#define CPREP_BLKS 96
#define WPREP_BLKS 192
// first 2*PLACE_BLKS blocks alternate place/embed so both run concurrently on
// every CU (grid-order dispatch had previously serialized them)
#define MEGA_BLKS (2 * PLACE_BLKS + (EMB_BLKS - PLACE_BLKS) + CPREP_BLKS + WPREP_BLKS + 7 + 1)

typedef __attribute__((ext_vector_type(8))) short short8;
typedef __attribute__((ext_vector_type(4))) float floatx4;
typedef __attribute__((ext_vector_type(4))) float fx4;
typedef unsigned short ush_t;
typedef __attribute__((ext_vector_type(8))) unsigned short ushort8_t;

__device__ __forceinline__ ush_t f2bf(float f) {
    unsigned u = __float_as_uint(f);
    return (ush_t)((u + 0x7fffu + ((u >> 16) & 1u)) >> 16);
}
__device__ __forceinline__ float bf2f(ush_t h) {
    return __uint_as_float((unsigned)h << 16);
}
__device__ __forceinline__ float sigf(float x) {
    return __builtin_amdgcn_rcpf(1.0f + __expf(-x));
}
__device__ __forceinline__ float tanhf_fast(float x) {
    x = fminf(fmaxf(x, -20.0f), 20.0f);
    float e = __expf(2.0f * x);
    return 1.0f - 2.0f * __builtin_amdgcn_rcpf(e + 1.0f);
}

// ---------------------------------------------------------------- mega-prep:
// place (single-pass fixed-slot edge table) ∥ embed ∥ cprep ∥ wprep ∥ rowmean ∥ accz.
__global__ __launch_bounds__(256) void mega_kernel(
        const int* __restrict__ src, const int* __restrict__ dst,
        const int* __restrict__ et, unsigned* __restrict__ csr,
        int* __restrict__ fill,
        const int* __restrict__ ids, const float* __restrict__ tab, ush_t* __restrict__ x,
        const float* __restrict__ Wih, const float* __restrict__ G,
        const float* __restrict__ Whh, ush_t* __restrict__ WB,
        const float* __restrict__ etab, float* __restrict__ rm,
        float* __restrict__ accz) {
    __shared__ float sW[16 * 128];
    int b = blockIdx.x;
    int t = threadIdx.x;
    int role;          // 0 = place, 1 = embed, 2 = rest
    int idx;
    if (b < 2 * PLACE_BLKS) {
        role = b & 1;
        idx = b >> 1;
    } else {
        int r = b - 2 * PLACE_BLKS;
        if (r < EMB_BLKS - PLACE_BLKS) { role = 1; idx = PLACE_BLKS + r; }
        else { role = 2; idx = r - (EMB_BLKS - PLACE_BLKS); }
    }
    if (role == 0) {
        // ---- single-pass placement: one atomic + one scattered 4B store per edge
        int e = idx * 256 + t;
        if (e < NE) {
            int d  = __builtin_nontemporal_load(dst + e);
            int s  = __builtin_nontemporal_load(src + e);
            int ty = __builtin_nontemporal_load(et + e);
            int pos = atomicAdd(&fill[d], 1);
            if (pos < SLOTS)
                csr[(size_t)d * SLOTS + pos] = (unsigned)s | ((unsigned)(ty - 1) << 17);
        }
        return;
    }
    if (role == 1) {
        // ---- embedding gather -> bf16 row-major
        int tid = idx * 256 + t;
        int n = tid >> 4, c = tid & 15;
        if (n >= NPAD) return;
        ushort8_t h;
        if (n < NN) {
            int id = __builtin_nontemporal_load(ids + n);
            const fx4* srcp = (const fx4*)(tab + (size_t)(id + 1) * DD + c * 8);
            fx4 v0 = __builtin_nontemporal_load(srcp);
            fx4 v1 = __builtin_nontemporal_load(srcp + 1);
            h[0] = f2bf(v0[0]); h[1] = f2bf(v0[1]); h[2] = f2bf(v0[2]); h[3] = f2bf(v0[3]);
            h[4] = f2bf(v1[0]); h[5] = f2bf(v1[1]); h[6] = f2bf(v1[2]); h[7] = f2bf(v1[3]);
        } else {
            #pragma unroll
            for (int e2 = 0; e2 < 8; ++e2) h[e2] = 0;
        }
        __builtin_nontemporal_store(h, (ushort8_t*)(x + (size_t)n * DD + c * 8));
        return;
    }
    int b2 = idx;
    if (b2 < CPREP_BLKS) {
        // ---- combined weights: C[l,g] = W_l @ Wih_g^T
        int mat = b2 >> 3, rg = b2 & 7;
        int l = mat / 3, g = mat % 3;
        int k0 = rg * 16;
        #pragma unroll
        for (int it = 0; it < 8; ++it) {
            int idx2 = it * 256 + t;
            sW[idx2] = G[(size_t)l * 16384 + (size_t)(k0 + (idx2 >> 7)) * 128 + (idx2 & 127)];
        }
        __syncthreads();
        int col = t & 127, kh = t >> 7;
        float acc[8];
        #pragma unroll
        for (int e2 = 0; e2 < 8; ++e2) acc[e2] = 0.f;
        const float* wr = Wih + (size_t)(g * 128 + col) * 128;
        for (int j = 0; j < 128; ++j) {
            float wv = wr[j];
            #pragma unroll
            for (int e2 = 0; e2 < 8; ++e2) acc[e2] += sW[(kh * 8 + e2) * 128 + j] * wv;
        }
        int M = 3 + l * 3 + g;
        #pragma unroll
        for (int e2 = 0; e2 < 8; ++e2) {
            int k = k0 + kh * 8 + e2;
            int chunk = k >> 5, klo = k & 31;
            int inoff = ((col >> 4) * 4 + (klo >> 3)) * 128 + (col & 15) * 8 + (klo & 7);
            WB[(size_t)(M * 4 + chunk) * 4096 + inoff] = f2bf(acc[e2]);
        }
        return;
    }
    b2 -= CPREP_BLKS;
    if (b2 < WPREP_BLKS) {
        // ---- Whh gates -> WB mats 0..2
        int idx2 = b2 * 256 + t;
        int mat = idx2 >> 14;
        int rem = idx2 & 16383;
        int col = rem & 127, kk = rem >> 7;
        float w = Whh[((size_t)mat * 128 + col) * 128 + kk];
        int chunk = kk >> 5, klo = kk & 31;
        int inoff = ((col >> 4) * 4 + (klo >> 3)) * 128 + (col & 15) * 8 + (klo & 7);
        WB[(size_t)(mat * 4 + chunk) * 4096 + inoff] = f2bf(w);
        return;
    }
    b2 -= WPREP_BLKS;
    if (b2 < 7) {
        // ---- row means of edge-type table (7 blocks)
        int r = b2;
        float v = (t < 128) ? etab[r * DD + t] : 0.f;
        #pragma unroll
        for (int o = 32; o > 0; o >>= 1) v += __shfl_xor(v, o);
        if ((t & 63) == 0) sW[t >> 6] = v;
        __syncthreads();
        if (t == 0) rm[r] = (sW[0] + sW[1]) * (1.0f / DD);
        return;
    }
    // ---- zero pooling accumulators (1 block)
    for (int i = t; i < 64 * 128 + 64; i += 256) accz[i] = 0.f;
}

// ---------------------------------------------------------------- slot-table gather: g = sum rm[et]*x[src]
// 16 lanes per node, 16-B row loads; unroll 8/4/1 for deeper MLP on the
// typical-degree (Poisson(8)) rows.
__global__ __launch_bounds__(512) void agg_kernel(const ush_t* __restrict__ x,
                                                  const int* __restrict__ fill,
                                                  const unsigned* __restrict__ csr,
                                                  const float* __restrict__ rm,
                                                  ush_t* __restrict__ gH) {
    __shared__ float srm[8];
    int t = threadIdx.x;
    if (t < 7) srm[t] = rm[t];
    __syncthreads();
    int grp = t >> 4, c = t & 15;
    int n = blockIdx.x * 32 + grp;
    if (n >= NPAD) return;
    int nout = ((n >> 7) << 14) + ((c >> 2) << 12) + (((n >> 4) & 7) << 9)
             + ((c & 3) << 7) + ((n & 15) << 3);
    if (n >= NN) {
        ushort8_t z;
        #pragma unroll
        for (int k = 0; k < 8; ++k) z[k] = 0;
        *(ushort8_t*)(gH + nout) = z;
        return;
    }
    const ush_t* xc = x + c * 8;
    const unsigned* cp = csr + (size_t)n * SLOTS;
    int cnt = fill[n];
    if (cnt > SLOTS) cnt = SLOTS;
    float acc[8];
    #pragma unroll
    for (int k = 0; k < 8; ++k) acc[k] = 0.f;
    int e = 0;
    for (; e + 7 < cnt; e += 8) {
        unsigned r[8];
        #pragma unroll
        for (int j = 0; j < 8; ++j) r[j] = cp[e + j];
        ushort8_t p[8];
        #pragma unroll
        for (int j = 0; j < 8; ++j)
            p[j] = *(const ushort8_t*)(xc + (size_t)(r[j] & 0x1FFFFu) * DD);
        #pragma unroll
        for (int j = 0; j < 8; ++j) {
            float w = srm[r[j] >> 17];
            #pragma unroll
            for (int k = 0; k < 8; ++k) acc[k] += w * bf2f(p[j][k]);
        }
    }
    for (; e + 3 < cnt; e += 4) {
        unsigned r0 = cp[e], r1 = cp[e + 1], r2 = cp[e + 2], r3 = cp[e + 3];
        float w0 = srm[r0 >> 17], w1 = srm[r1 >> 17];
        float w2 = srm[r2 >> 17], w3 = srm[r3 >> 17];
        ushort8_t p0 = *(const ushort8_t*)(xc + (size_t)(r0 & 0x1FFFFu) * DD);
        ushort8_t p1 = *(const ushort8_t*)(xc + (size_t)(r1 & 0x1FFFFu) * DD);
        ushort8_t p2 = *(const ushort8_t*)(xc + (size_t)(r2 & 0x1FFFFu) * DD);
        ushort8_t p3 = *(const ushort8_t*)(xc + (size_t)(r3 & 0x1FFFFu) * DD);
        #pragma unroll
        for (int k = 0; k < 8; ++k)
            acc[k] += w0 * bf2f(p0[k]) + w1 * bf2f(p1[k])
                    + w2 * bf2f(p2[k]) + w3 * bf2f(p3[k]);
    }
    for (; e < cnt; ++e) {
        unsigned r0 = cp[e];
        float w0 = srm[r0 >> 17];
        ushort8_t p0 = *(const ushort8_t*)(xc + (size_t)(r0 & 0x1FFFFu) * DD);
        #pragma unroll
        for (int k = 0; k < 8; ++k) acc[k] += w0 * bf2f(p0[k]);
    }
    ushort8_t oh;
    #pragma unroll
    for (int k = 0; k < 8; ++k) oh[k] = f2bf(acc[k]);
    *(ushort8_t*)(gH + nout) = oh;
}

// ---------------------------------------------------------------- GRU layer kernel (64-row tiles, 8 waves)
// (512,4): 128-VGPR budget, 64-reg acc, 4 waves/SIMD, 2 blocks/CU — the
// proven equilibrium (R9's 128-row/(512,2) variant lost 58 µs to phase
// bubbles at 1 block/CU).
__global__ __launch_bounds__(512, 4) void gru_kernel(const ush_t* __restrict__ xin,
                                                     const ush_t* __restrict__ gH,
                                                     ush_t* __restrict__ xout,
                                                     const ush_t* __restrict__ WB,
                                                     const float* __restrict__ bih,
                                                     const float* __restrict__ bhh,
                                                     int layer, int is_last,
                                                     const float* __restrict__ gw,
                                                     const float* __restrict__ gb,
                                                     float* __restrict__ accum,
                                                     float* __restrict__ den) {
    __shared__ ush_t sX[64 * 136];
    __shared__ ush_t sG[64 * 128];     // frag-plane chunk, linear
    __shared__ float pl[64];
    int t = threadIdx.x;
    int tb = blockIdx.x;
    int n0 = tb * 64;
    // --- stage x tile (row-major, padded pitch)
    #pragma unroll
    for (int it = 0; it < 2; ++it) {
        int idx = it * 512 + t;          // 1024 chunks of 16B
        int row = idx >> 4, seg = idx & 15;
        ushort8_t v = *(const ushort8_t*)(xin + (size_t)(n0 + row) * DD + seg * 8);
        *(ushort8_t*)(sX + row * 136 + seg * 8) = v;
    }
    // --- stage gH tile: block's data = 4 pieces of 2048 ush at 4096 stride
    {
        size_t gsrc = (size_t)(tb >> 1) * 16384 + (size_t)(tb & 1) * 2048;
        #pragma unroll
        for (int it = 0; it < 2; ++it) {
            int o = (it * 512 + t) * 8;                 // ush offset, 0..8191
            ushort8_t v = *(const ushort8_t*)(gH + gsrc + (o >> 11) * 4096 + (o & 2047));
            *(ushort8_t*)(sG + o) = v;
        }
    }
    __syncthreads();
    // --- MFMA
    int l = t & 63, w = t >> 6;          // w = 0..7: column tile
    int lg = l >> 4, lc = l & 15;
    floatx4 accR[4], accZ[4], accN[4], accI[4];
    #pragma unroll
    for (int i = 0; i < 4; ++i) {
        accR[i] = (floatx4)0.f; accZ[i] = (floatx4)0.f;
        accN[i] = (floatx4)0.f; accI[i] = (floatx4)0.f;
    }
    int boff = ((w * 4 + lg) * 16 + lc) * 8;
    #pragma unroll
    for (int pass = 0; pass < 2; ++pass) {
        int matbase = pass ? (3 + layer * 3) : 0;
        #pragma unroll
        for (int kc = 0; kc < 4; ++kc) {
            short8 aHf[4];
            if (pass == 0) {
                #pragma unroll
                for (int i = 0; i < 4; ++i)
                    aHf[i] = *(const short8*)(sX + (i * 16 + lc) * 136 + kc * 32 + lg * 8);
            } else {
                #pragma unroll
                for (int i = 0; i < 4; ++i)
                    aHf[i] = *(const short8*)(sG + kc * 2048 + i * 512 + lg * 128 + lc * 8);
            }
            #pragma unroll
            for (int m3 = 0; m3 < 3; ++m3) {
                floatx4* accp = (m3 == 0) ? accR : (m3 == 1) ? accZ : (pass ? accI : accN);
                const ush_t* wb = WB + (size_t)((matbase + m3) * 4 + kc) * 4096;
                short8 bH = *(const short8*)(wb + boff);
                #pragma unroll
                for (int i = 0; i < 4; ++i)
                    accp[i] = __builtin_amdgcn_mfma_f32_16x16x32_bf16(aHf[i], bH, accp[i], 0, 0, 0);
            }
        }
    }
    __syncthreads();   // all sX A-frag reads done before overwrite
    // --- gates + blend, in-place into sX
    {
        int col = w * 16 + lc;
        float bIr = bih[col],       bHr = bhh[col];
        float bIz = bih[128 + col], bHz = bhh[128 + col];
        float bIn = bih[256 + col], bHn = bhh[256 + col];
        #pragma unroll
        for (int i = 0; i < 4; ++i)
            #pragma unroll
            for (int r = 0; r < 4; ++r) {
                int row = i * 16 + lg * 4 + r;
                float v = 0.f;
                if (n0 + row < NN) {
                    float rr = sigf(accR[i][r] + bIr + bHr);
                    float zz = sigf(accZ[i][r] + bIz + bHz);
                    float nn = tanhf_fast(accI[i][r] + bIn + rr * (accN[i][r] + bHn));
                    float h = bf2f(sX[row * 136 + col]);
                    v = (1.0f - zz) * nn + zz * h;
                }
                sX[row * 136 + col] = f2bf(v);
            }
    }
    __syncthreads();
    if (!is_last) {
        // --- coalesced row-major write-out
        #pragma unroll
        for (int it = 0; it < 2; ++it) {
            int idx = it * 512 + t;
            int row = idx >> 4, seg = idx & 15;
            ushort8_t v = *(const ushort8_t*)(sX + row * 136 + seg * 8);
            *(ushort8_t*)(xout + (size_t)(n0 + row) * DD + seg * 8) = v;
        }
    } else {
        // --- fused global-attention pooling (replicated accumulators)
        int row = t >> 3, q = t & 7;      // 8 threads per row, 16 cols each
        float s = 0.f;
        #pragma unroll
        for (int e = 0; e < 16; ++e)
            s += bf2f(sX[row * 136 + q * 16 + e]) * gw[q * 16 + e];
        s += __shfl_xor(s, 1);
        s += __shfl_xor(s, 2);
        s += __shfl_xor(s, 4);
        if (q == 0)
            pl[row] = (n0 + row < NN) ? __expf(sigf(s + gb[0])) : 0.f;
        __syncthreads();
        int cc = t & 127, qr = t >> 7;    // 4 quarters of 16 rows each
        float acc = 0.f;
        #pragma unroll
        for (int r = 0; r < 16; ++r)
            acc += pl[qr * 16 + r] * bf2f(sX[(qr * 16 + r) * 136 + cc]);
        atomicAdd(&accum[(tb & 63) * 128 + cc], acc);
        if (t < 64) {
            float v = pl[t];
            #pragma unroll
            for (int o = 32; o > 0; o >>= 1) v += __shfl_xor(v, o);
            if (t == 0) atomicAdd(&den[tb & 63], v);
        }
    }
}

__global__ void finalize_kernel(const float* __restrict__ accum, const float* __restrict__ den,
                                float* __restrict__ out) {
    __shared__ float dsum;
    int d = threadIdx.x;   // 128
    float s = 0.f;
    for (int rep = 0; rep < 64; ++rep) s += accum[rep * 128 + d];
    if (d == 0) {
        float ds = 0.f;
        for (int rep = 0; rep < 64; ++rep) ds += den[rep];
        dsum = ds;
    }
    __syncthreads();
    out[d] = s / dsum;
}

// ---------------------------------------------------------------- launch
extern "C" void kernel_launch(void* const* d_in, const int* in_sizes, int n_in,
                              void* d_out, int out_size, void* d_ws, size_t ws_size,
                              hipStream_t stream) {
    const int*   node_ids    = (const int*)d_in[0];
    const int*   edges       = (const int*)d_in[1];
    const int*   edge_types  = (const int*)d_in[2];
    const float* embed_table = (const float*)d_in[3];
    const float* edge_tab    = (const float*)d_in[4];
    const float* ggnn_w      = (const float*)d_in[5];
    const float* Wih         = (const float*)d_in[6];
    const float* Whh         = (const float*)d_in[7];
    const float* bih         = (const float*)d_in[8];
    const float* bhh         = (const float*)d_in[9];
    const float* gate_w      = (const float*)d_in[10];
    const float* gate_b      = (const float*)d_in[11];
    float* out = (float*)d_out;

    const size_t PL = (size_t)NPAD * DD;
    ush_t* wsb  = (ush_t*)d_ws;
    ush_t* xA   = wsb;
    ush_t* xB   = xA + PL;
    ush_t* gH   = xB + PL;          // frag plane
    ush_t* WB   = gH + PL;          // 15 mats * 4 chunks * 4096
    unsigned* csr = (unsigned*)(WB + 15 * 4 * 4096);  // NPAD*SLOTS 4B records
    float* accum = (float*)(csr + (size_t)NPAD * SLOTS);  // 64 * 128
    float* den   = accum + 64 * 128;    // 64
    float* rm    = den + 64;            // 7(+1)
    int*   fill  = (int*)(rm + 8);      // N

    const int* src = edges;
    const int* dst = edges + NE;

    // prep: memset fill, then ONE mega kernel (place ∥ embed ∥ cprep ∥ wprep ∥ rowmean ∥ accz)
    hipMemsetAsync(fill, 0, NN * sizeof(int), stream);
    mega_kernel<<<MEGA_BLKS, 256, 0, stream>>>(src, dst, edge_types, csr, fill,
                                               node_ids, embed_table, xA,
                                               Wih, ggnn_w, Whh, WB,
                                               edge_tab, rm, accum);

    // 4 layers: standalone high-occupancy gather + gru
    ush_t* x = xA;
    ush_t* xo = xB;
    for (int layer = 0; layer < 4; ++layer) {
        agg_kernel<<<(NPAD + 31) / 32, 512, 0, stream>>>(x, fill, csr, rm, gH);
        gru_kernel<<<NT64, 512, 0, stream>>>(x, gH, xo, WB, bih, bhh,
                                             layer, layer == 3 ? 1 : 0,
                                             gate_w, gate_b, accum, den);
        ush_t* tmp = x; x = xo; xo = tmp;
    }

    finalize_kernel<<<1, 128, 0, stream>>>(accum, den, out);
}

// Round 11
// 459.880 us; speedup vs baseline: 1.1094x; 1.0138x over previous
//
#include <hip/hip_runtime.h>
#include <math.h>

#define NN 100000
#define NPAD 100096
#define NT64 1564     // NPAD / 64 (gru blocks)
#define NE 800000
#define DD 128
#define SLOTS 40      // fixed-slot edge table; Poisson(8) in-degree, P(>=40) ~ 6e-16

#define EMB_BLKS 6256     // NPAD*16/256
#define PLACE_BLKS 1563   // ceil(NE/512): 2 edges per thread (2 independent atomic chains/lane)
#define CPREP_BLKS 96
#define WPREP_BLKS 192
// first 2*PLACE_BLKS blocks alternate place/embed so both run concurrently on
// every CU; embed remainder, then the small preps.
#define MEGA_BLKS (2 * PLACE_BLKS + (EMB_BLKS - PLACE_BLKS) + CPREP_BLKS + WPREP_BLKS + 7 + 1)

typedef __attribute__((ext_vector_type(8))) short short8;
typedef __attribute__((ext_vector_type(4))) float floatx4;
typedef __attribute__((ext_vector_type(4))) float fx4;
typedef unsigned short ush_t;
typedef __attribute__((ext_vector_type(8))) unsigned short ushort8_t;

__device__ __forceinline__ ush_t f2bf(float f) {
    unsigned u = __float_as_uint(f);
    return (ush_t)((u + 0x7fffu + ((u >> 16) & 1u)) >> 16);
}
__device__ __forceinline__ float bf2f(ush_t h) {
    return __uint_as_float((unsigned)h << 16);
}
__device__ __forceinline__ float sigf(float x) {
    return __builtin_amdgcn_rcpf(1.0f + __expf(-x));
}
__device__ __forceinline__ float tanhf_fast(float x) {
    x = fminf(fmaxf(x, -20.0f), 20.0f);
    float e = __expf(2.0f * x);
    return 1.0f - 2.0f * __builtin_amdgcn_rcpf(e + 1.0f);
}

// ---------------------------------------------------------------- mega-prep:
// place (single-pass fixed-slot edge table) ∥ embed ∥ cprep ∥ wprep ∥ rowmean ∥ accz.
__global__ __launch_bounds__(256) void mega_kernel(
        const int* __restrict__ src, const int* __restrict__ dst,
        const int* __restrict__ et, unsigned* __restrict__ csr,
        int* __restrict__ fill,
        const int* __restrict__ ids, const float* __restrict__ tab, ush_t* __restrict__ x,
        const float* __restrict__ Wih, const float* __restrict__ G,
        const float* __restrict__ Whh, ush_t* __restrict__ WB,
        const float* __restrict__ etab, float* __restrict__ rm,
        float* __restrict__ accz) {
    __shared__ float sW[16 * 128];
    int b = blockIdx.x;
    int t = threadIdx.x;
    int role;          // 0 = place, 1 = embed, 2 = rest
    int idx;
    if (b < 2 * PLACE_BLKS) {
        role = b & 1;
        idx = b >> 1;
    } else {
        int r = b - 2 * PLACE_BLKS;
        if (r < EMB_BLKS - PLACE_BLKS) { role = 1; idx = PLACE_BLKS + r; }
        else { role = 2; idx = r - (EMB_BLKS - PLACE_BLKS); }
    }
    if (role == 0) {
        // ---- single-pass placement, 2 edges/thread: two INDEPENDENT
        // atomic->store chains per lane double the outstanding atomics per
        // wave (the phase is atomic-latency-bound, not BW-bound).
        int e0 = idx * 512 + t;
        int e1 = e0 + 256;
        int d0 = 0, s0 = 0, ty0 = 0, d1 = 0, s1 = 0, ty1 = 0;
        bool v0 = e0 < NE, v1 = e1 < NE;
        if (v0) {
            d0  = __builtin_nontemporal_load(dst + e0);
            s0  = __builtin_nontemporal_load(src + e0);
            ty0 = __builtin_nontemporal_load(et + e0);
        }
        if (v1) {
            d1  = __builtin_nontemporal_load(dst + e1);
            s1  = __builtin_nontemporal_load(src + e1);
            ty1 = __builtin_nontemporal_load(et + e1);
        }
        int p0 = 0, p1 = 0;
        if (v0) p0 = atomicAdd(&fill[d0], 1);
        if (v1) p1 = atomicAdd(&fill[d1], 1);
        if (v0 && p0 < SLOTS)
            csr[(size_t)d0 * SLOTS + p0] = (unsigned)s0 | ((unsigned)(ty0 - 1) << 17);
        if (v1 && p1 < SLOTS)
            csr[(size_t)d1 * SLOTS + p1] = (unsigned)s1 | ((unsigned)(ty1 - 1) << 17);
        return;
    }
    if (role == 1) {
        // ---- embedding gather -> bf16 row-major
        int tid = idx * 256 + t;
        int n = tid >> 4, c = tid & 15;
        if (n >= NPAD) return;
        ushort8_t h;
        if (n < NN) {
            int id = __builtin_nontemporal_load(ids + n);
            const fx4* srcp = (const fx4*)(tab + (size_t)(id + 1) * DD + c * 8);
            fx4 v0 = __builtin_nontemporal_load(srcp);
            fx4 v1 = __builtin_nontemporal_load(srcp + 1);
            h[0] = f2bf(v0[0]); h[1] = f2bf(v0[1]); h[2] = f2bf(v0[2]); h[3] = f2bf(v0[3]);
            h[4] = f2bf(v1[0]); h[5] = f2bf(v1[1]); h[6] = f2bf(v1[2]); h[7] = f2bf(v1[3]);
        } else {
            #pragma unroll
            for (int e2 = 0; e2 < 8; ++e2) h[e2] = 0;
        }
        __builtin_nontemporal_store(h, (ushort8_t*)(x + (size_t)n * DD + c * 8));
        return;
    }
    int b2 = idx;
    if (b2 < CPREP_BLKS) {
        // ---- combined weights: C[l,g] = W_l @ Wih_g^T
        int mat = b2 >> 3, rg = b2 & 7;
        int l = mat / 3, g = mat % 3;
        int k0 = rg * 16;
        #pragma unroll
        for (int it = 0; it < 8; ++it) {
            int idx2 = it * 256 + t;
            sW[idx2] = G[(size_t)l * 16384 + (size_t)(k0 + (idx2 >> 7)) * 128 + (idx2 & 127)];
        }
        __syncthreads();
        int col = t & 127, kh = t >> 7;
        float acc[8];
        #pragma unroll
        for (int e2 = 0; e2 < 8; ++e2) acc[e2] = 0.f;
        const float* wr = Wih + (size_t)(g * 128 + col) * 128;
        for (int j = 0; j < 128; ++j) {
            float wv = wr[j];
            #pragma unroll
            for (int e2 = 0; e2 < 8; ++e2) acc[e2] += sW[(kh * 8 + e2) * 128 + j] * wv;
        }
        int M = 3 + l * 3 + g;
        #pragma unroll
        for (int e2 = 0; e2 < 8; ++e2) {
            int k = k0 + kh * 8 + e2;
            int chunk = k >> 5, klo = k & 31;
            int inoff = ((col >> 4) * 4 + (klo >> 3)) * 128 + (col & 15) * 8 + (klo & 7);
            WB[(size_t)(M * 4 + chunk) * 4096 + inoff] = f2bf(acc[e2]);
        }
        return;
    }
    b2 -= CPREP_BLKS;
    if (b2 < WPREP_BLKS) {
        // ---- Whh gates -> WB mats 0..2
        int idx2 = b2 * 256 + t;
        int mat = idx2 >> 14;
        int rem = idx2 & 16383;
        int col = rem & 127, kk = rem >> 7;
        float w = Whh[((size_t)mat * 128 + col) * 128 + kk];
        int chunk = kk >> 5, klo = kk & 31;
        int inoff = ((col >> 4) * 4 + (klo >> 3)) * 128 + (col & 15) * 8 + (klo & 7);
        WB[(size_t)(mat * 4 + chunk) * 4096 + inoff] = f2bf(w);
        return;
    }
    b2 -= WPREP_BLKS;
    if (b2 < 7) {
        // ---- row means of edge-type table (7 blocks)
        int r = b2;
        float v = (t < 128) ? etab[r * DD + t] : 0.f;
        #pragma unroll
        for (int o = 32; o > 0; o >>= 1) v += __shfl_xor(v, o);
        if ((t & 63) == 0) sW[t >> 6] = v;
        __syncthreads();
        if (t == 0) rm[r] = (sW[0] + sW[1]) * (1.0f / DD);
        return;
    }
    // ---- zero pooling accumulators (1 block)
    for (int i = t; i < 64 * 128 + 64; i += 256) accz[i] = 0.f;
}

// ---------------------------------------------------------------- slot-table gather: g = sum rm[et]*x[src]
// 16 lanes per node, 16-B row loads; unroll 4/1 (R10: unroll-8 cost ~14 µs
// via VGPR pressure with no MLP gain at Poisson(8) degrees).
__global__ __launch_bounds__(512) void agg_kernel(const ush_t* __restrict__ x,
                                                  const int* __restrict__ fill,
                                                  const unsigned* __restrict__ csr,
                                                  const float* __restrict__ rm,
                                                  ush_t* __restrict__ gH) {
    __shared__ float srm[8];
    int t = threadIdx.x;
    if (t < 7) srm[t] = rm[t];
    __syncthreads();
    int grp = t >> 4, c = t & 15;
    int n = blockIdx.x * 32 + grp;
    if (n >= NPAD) return;
    int nout = ((n >> 7) << 14) + ((c >> 2) << 12) + (((n >> 4) & 7) << 9)
             + ((c & 3) << 7) + ((n & 15) << 3);
    if (n >= NN) {
        ushort8_t z;
        #pragma unroll
        for (int k = 0; k < 8; ++k) z[k] = 0;
        *(ushort8_t*)(gH + nout) = z;
        return;
    }
    const ush_t* xc = x + c * 8;
    const unsigned* cp = csr + (size_t)n * SLOTS;
    int cnt = fill[n];
    if (cnt > SLOTS) cnt = SLOTS;
    float acc[8];
    #pragma unroll
    for (int k = 0; k < 8; ++k) acc[k] = 0.f;
    int e = 0;
    for (; e + 3 < cnt; e += 4) {
        unsigned r0 = cp[e], r1 = cp[e + 1], r2 = cp[e + 2], r3 = cp[e + 3];
        float w0 = srm[r0 >> 17], w1 = srm[r1 >> 17];
        float w2 = srm[r2 >> 17], w3 = srm[r3 >> 17];
        ushort8_t p0 = *(const ushort8_t*)(xc + (size_t)(r0 & 0x1FFFFu) * DD);
        ushort8_t p1 = *(const ushort8_t*)(xc + (size_t)(r1 & 0x1FFFFu) * DD);
        ushort8_t p2 = *(const ushort8_t*)(xc + (size_t)(r2 & 0x1FFFFu) * DD);
        ushort8_t p3 = *(const ushort8_t*)(xc + (size_t)(r3 & 0x1FFFFu) * DD);
        #pragma unroll
        for (int k = 0; k < 8; ++k)
            acc[k] += w0 * bf2f(p0[k]) + w1 * bf2f(p1[k])
                    + w2 * bf2f(p2[k]) + w3 * bf2f(p3[k]);
    }
    for (; e < cnt; ++e) {
        unsigned r0 = cp[e];
        float w0 = srm[r0 >> 17];
        ushort8_t p0 = *(const ushort8_t*)(xc + (size_t)(r0 & 0x1FFFFu) * DD);
        #pragma unroll
        for (int k = 0; k < 8; ++k) acc[k] += w0 * bf2f(p0[k]);
    }
    ushort8_t oh;
    #pragma unroll
    for (int k = 0; k < 8; ++k) oh[k] = f2bf(acc[k]);
    *(ushort8_t*)(gH + nout) = oh;
}

// ---------------------------------------------------------------- GRU layer kernel (64-row tiles, 8 waves)
// (512,4): the proven equilibrium. s_setprio(1) wraps the MFMA cluster:
// gru runs 2 blocks/CU at independent phases (no inter-block barrier), the
// regime where setprio paid +4-7% on attn (m191) vs null on lockstep (m190).
__global__ __launch_bounds__(512, 4) void gru_kernel(const ush_t* __restrict__ xin,
                                                     const ush_t* __restrict__ gH,
                                                     ush_t* __restrict__ xout,
                                                     const ush_t* __restrict__ WB,
                                                     const float* __restrict__ bih,
                                                     const float* __restrict__ bhh,
                                                     int layer, int is_last,
                                                     const float* __restrict__ gw,
                                                     const float* __restrict__ gb,
                                                     float* __restrict__ accum,
                                                     float* __restrict__ den) {
    __shared__ ush_t sX[64 * 136];
    __shared__ ush_t sG[64 * 128];     // frag-plane chunk, linear
    __shared__ float pl[64];
    int t = threadIdx.x;
    int tb = blockIdx.x;
    int n0 = tb * 64;
    // --- stage x tile (row-major, padded pitch)
    #pragma unroll
    for (int it = 0; it < 2; ++it) {
        int idx = it * 512 + t;          // 1024 chunks of 16B
        int row = idx >> 4, seg = idx & 15;
        ushort8_t v = *(const ushort8_t*)(xin + (size_t)(n0 + row) * DD + seg * 8);
        *(ushort8_t*)(sX + row * 136 + seg * 8) = v;
    }
    // --- stage gH tile: block's data = 4 pieces of 2048 ush at 4096 stride
    {
        size_t gsrc = (size_t)(tb >> 1) * 16384 + (size_t)(tb & 1) * 2048;
        #pragma unroll
        for (int it = 0; it < 2; ++it) {
            int o = (it * 512 + t) * 8;                 // ush offset, 0..8191
            ushort8_t v = *(const ushort8_t*)(gH + gsrc + (o >> 11) * 4096 + (o & 2047));
            *(ushort8_t*)(sG + o) = v;
        }
    }
    __syncthreads();
    // --- MFMA
    int l = t & 63, w = t >> 6;          // w = 0..7: column tile
    int lg = l >> 4, lc = l & 15;
    floatx4 accR[4], accZ[4], accN[4], accI[4];
    #pragma unroll
    for (int i = 0; i < 4; ++i) {
        accR[i] = (floatx4)0.f; accZ[i] = (floatx4)0.f;
        accN[i] = (floatx4)0.f; accI[i] = (floatx4)0.f;
    }
    int boff = ((w * 4 + lg) * 16 + lc) * 8;
    __builtin_amdgcn_s_setprio(1);
    #pragma unroll
    for (int pass = 0; pass < 2; ++pass) {
        int matbase = pass ? (3 + layer * 3) : 0;
        #pragma unroll
        for (int kc = 0; kc < 4; ++kc) {
            short8 aHf[4];
            if (pass == 0) {
                #pragma unroll
                for (int i = 0; i < 4; ++i)
                    aHf[i] = *(const short8*)(sX + (i * 16 + lc) * 136 + kc * 32 + lg * 8);
            } else {
                #pragma unroll
                for (int i = 0; i < 4; ++i)
                    aHf[i] = *(const short8*)(sG + kc * 2048 + i * 512 + lg * 128 + lc * 8);
            }
            #pragma unroll
            for (int m3 = 0; m3 < 3; ++m3) {
                floatx4* accp = (m3 == 0) ? accR : (m3 == 1) ? accZ : (pass ? accI : accN);
                const ush_t* wb = WB + (size_t)((matbase + m3) * 4 + kc) * 4096;
                short8 bH = *(const short8*)(wb + boff);
                #pragma unroll
                for (int i = 0; i < 4; ++i)
                    accp[i] = __builtin_amdgcn_mfma_f32_16x16x32_bf16(aHf[i], bH, accp[i], 0, 0, 0);
            }
        }
    }
    __builtin_amdgcn_s_setprio(0);
    __syncthreads();   // all sX A-frag reads done before overwrite
    // --- gates + blend, in-place into sX
    {
        int col = w * 16 + lc;
        float bIr = bih[col],       bHr = bhh[col];
        float bIz = bih[128 + col], bHz = bhh[128 + col];
        float bIn = bih[256 + col], bHn = bhh[256 + col];
        #pragma unroll
        for (int i = 0; i < 4; ++i)
            #pragma unroll
            for (int r = 0; r < 4; ++r) {
                int row = i * 16 + lg * 4 + r;
                float v = 0.f;
                if (n0 + row < NN) {
                    float rr = sigf(accR[i][r] + bIr + bHr);
                    float zz = sigf(accZ[i][r] + bIz + bHz);
                    float nn = tanhf_fast(accI[i][r] + bIn + rr * (accN[i][r] + bHn));
                    float h = bf2f(sX[row * 136 + col]);
                    v = (1.0f - zz) * nn + zz * h;
                }
                sX[row * 136 + col] = f2bf(v);
            }
    }
    __syncthreads();
    if (!is_last) {
        // --- coalesced row-major write-out
        #pragma unroll
        for (int it = 0; it < 2; ++it) {
            int idx = it * 512 + t;
            int row = idx >> 4, seg = idx & 15;
            ushort8_t v = *(const ushort8_t*)(sX + row * 136 + seg * 8);
            *(ushort8_t*)(xout + (size_t)(n0 + row) * DD + seg * 8) = v;
        }
    } else {
        // --- fused global-attention pooling (replicated accumulators)
        int row = t >> 3, q = t & 7;      // 8 threads per row, 16 cols each
        float s = 0.f;
        #pragma unroll
        for (int e = 0; e < 16; ++e)
            s += bf2f(sX[row * 136 + q * 16 + e]) * gw[q * 16 + e];
        s += __shfl_xor(s, 1);
        s += __shfl_xor(s, 2);
        s += __shfl_xor(s, 4);
        if (q == 0)
            pl[row] = (n0 + row < NN) ? __expf(sigf(s + gb[0])) : 0.f;
        __syncthreads();
        int cc = t & 127, qr = t >> 7;    // 4 quarters of 16 rows each
        float acc = 0.f;
        #pragma unroll
        for (int r = 0; r < 16; ++r)
            acc += pl[qr * 16 + r] * bf2f(sX[(qr * 16 + r) * 136 + cc]);
        atomicAdd(&accum[(tb & 63) * 128 + cc], acc);
        if (t < 64) {
            float v = pl[t];
            #pragma unroll
            for (int o = 32; o > 0; o >>= 1) v += __shfl_xor(v, o);
            if (t == 0) atomicAdd(&den[tb & 63], v);
        }
    }
}

__global__ void finalize_kernel(const float* __restrict__ accum, const float* __restrict__ den,
                                float* __restrict__ out) {
    __shared__ float dsum;
    int d = threadIdx.x;   // 128
    float s = 0.f;
    for (int rep = 0; rep < 64; ++rep) s += accum[rep * 128 + d];
    if (d == 0) {
        float ds = 0.f;
        for (int rep = 0; rep < 64; ++rep) ds += den[rep];
        dsum = ds;
    }
    __syncthreads();
    out[d] = s / dsum;
}

// ---------------------------------------------------------------- launch
extern "C" void kernel_launch(void* const* d_in, const int* in_sizes, int n_in,
                              void* d_out, int out_size, void* d_ws, size_t ws_size,
                              hipStream_t stream) {
    const int*   node_ids    = (const int*)d_in[0];
    const int*   edges       = (const int*)d_in[1];
    const int*   edge_types  = (const int*)d_in[2];
    const float* embed_table = (const float*)d_in[3];
    const float* edge_tab    = (const float*)d_in[4];
    const float* ggnn_w      = (const float*)d_in[5];
    const float* Wih         = (const float*)d_in[6];
    const float* Whh         = (const float*)d_in[7];
    const float* bih         = (const float*)d_in[8];
    const float* bhh         = (const float*)d_in[9];
    const float* gate_w      = (const float*)d_in[10];
    const float* gate_b      = (const float*)d_in[11];
    float* out = (float*)d_out;

    const size_t PL = (size_t)NPAD * DD;
    ush_t* wsb  = (ush_t*)d_ws;
    ush_t* xA   = wsb;
    ush_t* xB   = xA + PL;
    ush_t* gH   = xB + PL;          // frag plane
    ush_t* WB   = gH + PL;          // 15 mats * 4 chunks * 4096
    unsigned* csr = (unsigned*)(WB + 15 * 4 * 4096);  // NPAD*SLOTS 4B records
    float* accum = (float*)(csr + (size_t)NPAD * SLOTS);  // 64 * 128
    float* den   = accum + 64 * 128;    // 64
    float* rm    = den + 64;            // 7(+1)
    int*   fill  = (int*)(rm + 8);      // N

    const int* src = edges;
    const int* dst = edges + NE;

    // prep: memset fill, then ONE mega kernel (place ∥ embed ∥ cprep ∥ wprep ∥ rowmean ∥ accz)
    hipMemsetAsync(fill, 0, NN * sizeof(int), stream);
    mega_kernel<<<MEGA_BLKS, 256, 0, stream>>>(src, dst, edge_types, csr, fill,
                                               node_ids, embed_table, xA,
                                               Wih, ggnn_w, Whh, WB,
                                               edge_tab, rm, accum);

    // 4 layers: standalone high-occupancy gather + gru
    ush_t* x = xA;
    ush_t* xo = xB;
    for (int layer = 0; layer < 4; ++layer) {
        agg_kernel<<<(NPAD + 31) / 32, 512, 0, stream>>>(x, fill, csr, rm, gH);
        gru_kernel<<<NT64, 512, 0, stream>>>(x, gH, xo, WB, bih, bhh,
                                             layer, layer == 3 ? 1 : 0,
                                             gate_w, gate_b, accum, den);
        ush_t* tmp = x; x = xo; xo = tmp;
    }

    finalize_kernel<<<1, 128, 0, stream>>>(accum, den, out);
}

// Round 12
// 455.221 us; speedup vs baseline: 1.1208x; 1.0102x over previous
//
#include <hip/hip_runtime.h>
#include <math.h>

#define NN 100000
#define NPAD 100096
#define NT64 1564     // NPAD / 64 (gru blocks)
#define NE 800000
#define DD 128
#define SLOTS 40      // fixed-slot edge table; Poisson(8) in-degree, P(>=40) ~ 6e-16

#define EMB_BLKS 6256     // NPAD*16/256
#define PLACE_BLKS 3125   // NE/256 (1 edge/thread; R11: 2 edges/thread was +3 µs)
#define CPREP_BLKS 96
#define WPREP_BLKS 192
// first 2*PLACE_BLKS blocks alternate place/embed so both run concurrently on
// every CU (grid-order dispatch had previously serialized them)
#define MEGA_BLKS (2 * PLACE_BLKS + (EMB_BLKS - PLACE_BLKS) + CPREP_BLKS + WPREP_BLKS + 7 + 1)

typedef __attribute__((ext_vector_type(8))) short short8;
typedef __attribute__((ext_vector_type(4))) float floatx4;
typedef __attribute__((ext_vector_type(4))) float fx4;
typedef unsigned short ush_t;
typedef __attribute__((ext_vector_type(8))) unsigned short ushort8_t;

__device__ __forceinline__ ush_t f2bf(float f) {
    unsigned u = __float_as_uint(f);
    return (ush_t)((u + 0x7fffu + ((u >> 16) & 1u)) >> 16);
}
__device__ __forceinline__ float bf2f(ush_t h) {
    return __uint_as_float((unsigned)h << 16);
}
__device__ __forceinline__ float sigf(float x) {
    return __builtin_amdgcn_rcpf(1.0f + __expf(-x));
}
__device__ __forceinline__ float tanhf_fast(float x) {
    x = fminf(fmaxf(x, -20.0f), 20.0f);
    float e = __expf(2.0f * x);
    return 1.0f - 2.0f * __builtin_amdgcn_rcpf(e + 1.0f);
}

// ---------------------------------------------------------------- mega-prep:
// place (single-pass fixed-slot edge table) ∥ embed ∥ cprep ∥ wprep ∥ rowmean ∥ accz.
__global__ __launch_bounds__(256) void mega_kernel(
        const int* __restrict__ src, const int* __restrict__ dst,
        const int* __restrict__ et, unsigned* __restrict__ csr,
        int* __restrict__ fill,
        const int* __restrict__ ids, const float* __restrict__ tab, ush_t* __restrict__ x,
        const float* __restrict__ Wih, const float* __restrict__ G,
        const float* __restrict__ Whh, ush_t* __restrict__ WB,
        const float* __restrict__ etab, float* __restrict__ rm,
        float* __restrict__ accz) {
    __shared__ float sW[16 * 128];
    int b = blockIdx.x;
    int t = threadIdx.x;
    int role;          // 0 = place, 1 = embed, 2 = rest
    int idx;
    if (b < 2 * PLACE_BLKS) {
        role = b & 1;
        idx = b >> 1;
    } else {
        int r = b - 2 * PLACE_BLKS;
        if (r < EMB_BLKS - PLACE_BLKS) { role = 1; idx = PLACE_BLKS + r; }
        else { role = 2; idx = r - (EMB_BLKS - PLACE_BLKS); }
    }
    if (role == 0) {
        // ---- single-pass placement: one atomic + one scattered 4B store per edge
        int e = idx * 256 + t;
        if (e < NE) {
            int d  = __builtin_nontemporal_load(dst + e);
            int s  = __builtin_nontemporal_load(src + e);
            int ty = __builtin_nontemporal_load(et + e);
            int pos = atomicAdd(&fill[d], 1);
            if (pos < SLOTS)
                csr[(size_t)d * SLOTS + pos] = (unsigned)s | ((unsigned)(ty - 1) << 17);
        }
        return;
    }
    if (role == 1) {
        // ---- embedding gather -> bf16 row-major
        int tid = idx * 256 + t;
        int n = tid >> 4, c = tid & 15;
        if (n >= NPAD) return;
        ushort8_t h;
        if (n < NN) {
            int id = __builtin_nontemporal_load(ids + n);
            const fx4* srcp = (const fx4*)(tab + (size_t)(id + 1) * DD + c * 8);
            fx4 v0 = __builtin_nontemporal_load(srcp);
            fx4 v1 = __builtin_nontemporal_load(srcp + 1);
            h[0] = f2bf(v0[0]); h[1] = f2bf(v0[1]); h[2] = f2bf(v0[2]); h[3] = f2bf(v0[3]);
            h[4] = f2bf(v1[0]); h[5] = f2bf(v1[1]); h[6] = f2bf(v1[2]); h[7] = f2bf(v1[3]);
        } else {
            #pragma unroll
            for (int e2 = 0; e2 < 8; ++e2) h[e2] = 0;
        }
        __builtin_nontemporal_store(h, (ushort8_t*)(x + (size_t)n * DD + c * 8));
        return;
    }
    int b2 = idx;
    if (b2 < CPREP_BLKS) {
        // ---- combined weights: C[l,g] = W_l @ Wih_g^T
        int mat = b2 >> 3, rg = b2 & 7;
        int l = mat / 3, g = mat % 3;
        int k0 = rg * 16;
        #pragma unroll
        for (int it = 0; it < 8; ++it) {
            int idx2 = it * 256 + t;
            sW[idx2] = G[(size_t)l * 16384 + (size_t)(k0 + (idx2 >> 7)) * 128 + (idx2 & 127)];
        }
        __syncthreads();
        int col = t & 127, kh = t >> 7;
        float acc[8];
        #pragma unroll
        for (int e2 = 0; e2 < 8; ++e2) acc[e2] = 0.f;
        const float* wr = Wih + (size_t)(g * 128 + col) * 128;
        for (int j = 0; j < 128; ++j) {
            float wv = wr[j];
            #pragma unroll
            for (int e2 = 0; e2 < 8; ++e2) acc[e2] += sW[(kh * 8 + e2) * 128 + j] * wv;
        }
        int M = 3 + l * 3 + g;
        #pragma unroll
        for (int e2 = 0; e2 < 8; ++e2) {
            int k = k0 + kh * 8 + e2;
            int chunk = k >> 5, klo = k & 31;
            int inoff = ((col >> 4) * 4 + (klo >> 3)) * 128 + (col & 15) * 8 + (klo & 7);
            WB[(size_t)(M * 4 + chunk) * 4096 + inoff] = f2bf(acc[e2]);
        }
        return;
    }
    b2 -= CPREP_BLKS;
    if (b2 < WPREP_BLKS) {
        // ---- Whh gates -> WB mats 0..2
        int idx2 = b2 * 256 + t;
        int mat = idx2 >> 14;
        int rem = idx2 & 16383;
        int col = rem & 127, kk = rem >> 7;
        float w = Whh[((size_t)mat * 128 + col) * 128 + kk];
        int chunk = kk >> 5, klo = kk & 31;
        int inoff = ((col >> 4) * 4 + (klo >> 3)) * 128 + (col & 15) * 8 + (klo & 7);
        WB[(size_t)(mat * 4 + chunk) * 4096 + inoff] = f2bf(w);
        return;
    }
    b2 -= WPREP_BLKS;
    if (b2 < 7) {
        // ---- row means of edge-type table (7 blocks)
        int r = b2;
        float v = (t < 128) ? etab[r * DD + t] : 0.f;
        #pragma unroll
        for (int o = 32; o > 0; o >>= 1) v += __shfl_xor(v, o);
        if ((t & 63) == 0) sW[t >> 6] = v;
        __syncthreads();
        if (t == 0) rm[r] = (sW[0] + sW[1]) * (1.0f / DD);
        return;
    }
    // ---- zero pooling accumulators (1 block)
    for (int i = t; i < 64 * 128 + 64; i += 256) accz[i] = 0.f;
}

// ---------------------------------------------------------------- slot-table gather: g = sum rm[et]*x[src]
// 16 lanes per node, 16-B row loads; unroll 4/1 (R10: unroll-8 cost ~14 µs
// via VGPR pressure with no MLP gain at Poisson(8) degrees).
__global__ __launch_bounds__(512) void agg_kernel(const ush_t* __restrict__ x,
                                                  const int* __restrict__ fill,
                                                  const unsigned* __restrict__ csr,
                                                  const float* __restrict__ rm,
                                                  ush_t* __restrict__ gH) {
    __shared__ float srm[8];
    int t = threadIdx.x;
    if (t < 7) srm[t] = rm[t];
    __syncthreads();
    int grp = t >> 4, c = t & 15;
    int n = blockIdx.x * 32 + grp;
    if (n >= NPAD) return;
    int nout = ((n >> 7) << 14) + ((c >> 2) << 12) + (((n >> 4) & 7) << 9)
             + ((c & 3) << 7) + ((n & 15) << 3);
    if (n >= NN) {
        ushort8_t z;
        #pragma unroll
        for (int k = 0; k < 8; ++k) z[k] = 0;
        *(ushort8_t*)(gH + nout) = z;
        return;
    }
    const ush_t* xc = x + c * 8;
    const unsigned* cp = csr + (size_t)n * SLOTS;
    int cnt = fill[n];
    if (cnt > SLOTS) cnt = SLOTS;
    float acc[8];
    #pragma unroll
    for (int k = 0; k < 8; ++k) acc[k] = 0.f;
    int e = 0;
    for (; e + 3 < cnt; e += 4) {
        unsigned r0 = cp[e], r1 = cp[e + 1], r2 = cp[e + 2], r3 = cp[e + 3];
        float w0 = srm[r0 >> 17], w1 = srm[r1 >> 17];
        float w2 = srm[r2 >> 17], w3 = srm[r3 >> 17];
        ushort8_t p0 = *(const ushort8_t*)(xc + (size_t)(r0 & 0x1FFFFu) * DD);
        ushort8_t p1 = *(const ushort8_t*)(xc + (size_t)(r1 & 0x1FFFFu) * DD);
        ushort8_t p2 = *(const ushort8_t*)(xc + (size_t)(r2 & 0x1FFFFu) * DD);
        ushort8_t p3 = *(const ushort8_t*)(xc + (size_t)(r3 & 0x1FFFFu) * DD);
        #pragma unroll
        for (int k = 0; k < 8; ++k)
            acc[k] += w0 * bf2f(p0[k]) + w1 * bf2f(p1[k])
                    + w2 * bf2f(p2[k]) + w3 * bf2f(p3[k]);
    }
    for (; e < cnt; ++e) {
        unsigned r0 = cp[e];
        float w0 = srm[r0 >> 17];
        ushort8_t p0 = *(const ushort8_t*)(xc + (size_t)(r0 & 0x1FFFFu) * DD);
        #pragma unroll
        for (int k = 0; k < 8; ++k) acc[k] += w0 * bf2f(p0[k]);
    }
    ushort8_t oh;
    #pragma unroll
    for (int k = 0; k < 8; ++k) oh[k] = f2bf(acc[k]);
    *(ushort8_t*)(gH + nout) = oh;
}

// ---------------------------------------------------------------- GRU layer kernel (64-row tiles, 8 waves)
// (512,4): 128-VGPR budget, 64-reg acc, 4 waves/SIMD, 2 blocks/CU — the
// proven equilibrium. Measured-worse alternatives: 128-row/(512,2) (R9,
// +58 µs: phase bubbles at 1 block/CU), setprio around MFMA (R11, null:
// intra-block waves are barrier-lockstep, nothing for the scheduler to
// arbitrate — m190's GEMM-null regime).
__global__ __launch_bounds__(512, 4) void gru_kernel(const ush_t* __restrict__ xin,
                                                     const ush_t* __restrict__ gH,
                                                     ush_t* __restrict__ xout,
                                                     const ush_t* __restrict__ WB,
                                                     const float* __restrict__ bih,
                                                     const float* __restrict__ bhh,
                                                     int layer, int is_last,
                                                     const float* __restrict__ gw,
                                                     const float* __restrict__ gb,
                                                     float* __restrict__ accum,
                                                     float* __restrict__ den) {
    __shared__ ush_t sX[64 * 136];
    __shared__ ush_t sG[64 * 128];     // frag-plane chunk, linear
    __shared__ float pl[64];
    int t = threadIdx.x;
    int tb = blockIdx.x;
    int n0 = tb * 64;
    // --- stage x tile (row-major, padded pitch)
    #pragma unroll
    for (int it = 0; it < 2; ++it) {
        int idx = it * 512 + t;          // 1024 chunks of 16B
        int row = idx >> 4, seg = idx & 15;
        ushort8_t v = *(const ushort8_t*)(xin + (size_t)(n0 + row) * DD + seg * 8);
        *(ushort8_t*)(sX + row * 136 + seg * 8) = v;
    }
    // --- stage gH tile: block's data = 4 pieces of 2048 ush at 4096 stride
    {
        size_t gsrc = (size_t)(tb >> 1) * 16384 + (size_t)(tb & 1) * 2048;
        #pragma unroll
        for (int it = 0; it < 2; ++it) {
            int o = (it * 512 + t) * 8;                 // ush offset, 0..8191
            ushort8_t v = *(const ushort8_t*)(gH + gsrc + (o >> 11) * 4096 + (o & 2047));
            *(ushort8_t*)(sG + o) = v;
        }
    }
    __syncthreads();
    // --- MFMA
    int l = t & 63, w = t >> 6;          // w = 0..7: column tile
    int lg = l >> 4, lc = l & 15;
    floatx4 accR[4], accZ[4], accN[4], accI[4];
    #pragma unroll
    for (int i = 0; i < 4; ++i) {
        accR[i] = (floatx4)0.f; accZ[i] = (floatx4)0.f;
        accN[i] = (floatx4)0.f; accI[i] = (floatx4)0.f;
    }
    int boff = ((w * 4 + lg) * 16 + lc) * 8;
    #pragma unroll
    for (int pass = 0; pass < 2; ++pass) {
        int matbase = pass ? (3 + layer * 3) : 0;
        #pragma unroll
        for (int kc = 0; kc < 4; ++kc) {
            short8 aHf[4];
            if (pass == 0) {
                #pragma unroll
                for (int i = 0; i < 4; ++i)
                    aHf[i] = *(const short8*)(sX + (i * 16 + lc) * 136 + kc * 32 + lg * 8);
            } else {
                #pragma unroll
                for (int i = 0; i < 4; ++i)
                    aHf[i] = *(const short8*)(sG + kc * 2048 + i * 512 + lg * 128 + lc * 8);
            }
            #pragma unroll
            for (int m3 = 0; m3 < 3; ++m3) {
                floatx4* accp = (m3 == 0) ? accR : (m3 == 1) ? accZ : (pass ? accI : accN);
                const ush_t* wb = WB + (size_t)((matbase + m3) * 4 + kc) * 4096;
                short8 bH = *(const short8*)(wb + boff);
                #pragma unroll
                for (int i = 0; i < 4; ++i)
                    accp[i] = __builtin_amdgcn_mfma_f32_16x16x32_bf16(aHf[i], bH, accp[i], 0, 0, 0);
            }
        }
    }
    __syncthreads();   // all sX A-frag reads done before overwrite
    // --- gates + blend, in-place into sX
    {
        int col = w * 16 + lc;
        float bIr = bih[col],       bHr = bhh[col];
        float bIz = bih[128 + col], bHz = bhh[128 + col];
        float bIn = bih[256 + col], bHn = bhh[256 + col];
        #pragma unroll
        for (int i = 0; i < 4; ++i)
            #pragma unroll
            for (int r = 0; r < 4; ++r) {
                int row = i * 16 + lg * 4 + r;
                float v = 0.f;
                if (n0 + row < NN) {
                    float rr = sigf(accR[i][r] + bIr + bHr);
                    float zz = sigf(accZ[i][r] + bIz + bHz);
                    float nn = tanhf_fast(accI[i][r] + bIn + rr * (accN[i][r] + bHn));
                    float h = bf2f(sX[row * 136 + col]);
                    v = (1.0f - zz) * nn + zz * h;
                }
                sX[row * 136 + col] = f2bf(v);
            }
    }
    __syncthreads();
    if (!is_last) {
        // --- coalesced row-major write-out
        #pragma unroll
        for (int it = 0; it < 2; ++it) {
            int idx = it * 512 + t;
            int row = idx >> 4, seg = idx & 15;
            ushort8_t v = *(const ushort8_t*)(sX + row * 136 + seg * 8);
            *(ushort8_t*)(xout + (size_t)(n0 + row) * DD + seg * 8) = v;
        }
    } else {
        // --- fused global-attention pooling (replicated accumulators)
        int row = t >> 3, q = t & 7;      // 8 threads per row, 16 cols each
        float s = 0.f;
        #pragma unroll
        for (int e = 0; e < 16; ++e)
            s += bf2f(sX[row * 136 + q * 16 + e]) * gw[q * 16 + e];
        s += __shfl_xor(s, 1);
        s += __shfl_xor(s, 2);
        s += __shfl_xor(s, 4);
        if (q == 0)
            pl[row] = (n0 + row < NN) ? __expf(sigf(s + gb[0])) : 0.f;
        __syncthreads();
        int cc = t & 127, qr = t >> 7;    // 4 quarters of 16 rows each
        float acc = 0.f;
        #pragma unroll
        for (int r = 0; r < 16; ++r)
            acc += pl[qr * 16 + r] * bf2f(sX[(qr * 16 + r) * 136 + cc]);
        atomicAdd(&accum[(tb & 63) * 128 + cc], acc);
        if (t < 64) {
            float v = pl[t];
            #pragma unroll
            for (int o = 32; o > 0; o >>= 1) v += __shfl_xor(v, o);
            if (t == 0) atomicAdd(&den[tb & 63], v);
        }
    }
}

__global__ void finalize_kernel(const float* __restrict__ accum, const float* __restrict__ den,
                                float* __restrict__ out) {
    __shared__ float dsum;
    int d = threadIdx.x;   // 128
    float s = 0.f;
    for (int rep = 0; rep < 64; ++rep) s += accum[rep * 128 + d];
    if (d == 0) {
        float ds = 0.f;
        for (int rep = 0; rep < 64; ++rep) ds += den[rep];
        dsum = ds;
    }
    __syncthreads();
    out[d] = s / dsum;
}

// ---------------------------------------------------------------- launch
extern "C" void kernel_launch(void* const* d_in, const int* in_sizes, int n_in,
                              void* d_out, int out_size, void* d_ws, size_t ws_size,
                              hipStream_t stream) {
    const int*   node_ids    = (const int*)d_in[0];
    const int*   edges       = (const int*)d_in[1];
    const int*   edge_types  = (const int*)d_in[2];
    const float* embed_table = (const float*)d_in[3];
    const float* edge_tab    = (const float*)d_in[4];
    const float* ggnn_w      = (const float*)d_in[5];
    const float* Wih         = (const float*)d_in[6];
    const float* Whh         = (const float*)d_in[7];
    const float* bih         = (const float*)d_in[8];
    const float* bhh         = (const float*)d_in[9];
    const float* gate_w      = (const float*)d_in[10];
    const float* gate_b      = (const float*)d_in[11];
    float* out = (float*)d_out;

    const size_t PL = (size_t)NPAD * DD;
    ush_t* wsb  = (ush_t*)d_ws;
    ush_t* xA   = wsb;
    ush_t* xB   = xA + PL;
    ush_t* gH   = xB + PL;          // frag plane
    ush_t* WB   = gH + PL;          // 15 mats * 4 chunks * 4096
    unsigned* csr = (unsigned*)(WB + 15 * 4 * 4096);  // NPAD*SLOTS 4B records
    float* accum = (float*)(csr + (size_t)NPAD * SLOTS);  // 64 * 128
    float* den   = accum + 64 * 128;    // 64
    float* rm    = den + 64;            // 7(+1)
    int*   fill  = (int*)(rm + 8);      // N

    const int* src = edges;
    const int* dst = edges + NE;

    // prep: memset fill, then ONE mega kernel (place ∥ embed ∥ cprep ∥ wprep ∥ rowmean ∥ accz)
    hipMemsetAsync(fill, 0, NN * sizeof(int), stream);
    mega_kernel<<<MEGA_BLKS, 256, 0, stream>>>(src, dst, edge_types, csr, fill,
                                               node_ids, embed_table, xA,
                                               Wih, ggnn_w, Whh, WB,
                                               edge_tab, rm, accum);

    // 4 layers: standalone high-occupancy gather + gru
    ush_t* x = xA;
    ush_t* xo = xB;
    for (int layer = 0; layer < 4; ++layer) {
        agg_kernel<<<(NPAD + 31) / 32, 512, 0, stream>>>(x, fill, csr, rm, gH);
        gru_kernel<<<NT64, 512, 0, stream>>>(x, gH, xo, WB, bih, bhh,
                                             layer, layer == 3 ? 1 : 0,
                                             gate_w, gate_b, accum, den);
        ush_t* tmp = x; x = xo; xo = tmp;
    }

    finalize_kernel<<<1, 128, 0, stream>>>(accum, den, out);
}

// Round 14
// 435.881 us; speedup vs baseline: 1.1705x; 1.0444x over previous
//
#include <hip/hip_runtime.h>
#include <math.h>

#define NN 100000
#define NPAD 100096
#define NT64 1564     // NPAD / 64 (gru blocks)
#define NE 800000
#define DD 128
#define SLOTS 40      // fixed-slot edge table; Poisson(8) in-degree, P(>=40) ~ 6e-16

#define EMB_BLKS 6256     // NPAD*16/256
#define PLACE_BLKS 3125   // NE/256 (1 edge/thread)
#define CPREP_BLKS 96
#define WPREP_BLKS 192
#define MEGA_BLKS (2 * PLACE_BLKS + (EMB_BLKS - PLACE_BLKS) + CPREP_BLKS + WPREP_BLKS + 7 + 1)

typedef __attribute__((ext_vector_type(8))) short short8;
typedef __attribute__((ext_vector_type(4))) float floatx4;
typedef __attribute__((ext_vector_type(2))) float floatx2;
typedef __attribute__((ext_vector_type(4))) float fx4;
typedef unsigned short ush_t;
typedef __attribute__((ext_vector_type(8))) unsigned short ushort8_t;

__device__ __forceinline__ ush_t f2bf(float f) {
    unsigned u = __float_as_uint(f);
    return (ush_t)((u + 0x7fffu + ((u >> 16) & 1u)) >> 16);
}
__device__ __forceinline__ float bf2f(ush_t h) {
    return __uint_as_float((unsigned)h << 16);
}
__device__ __forceinline__ float sigf(float x) {
    return __builtin_amdgcn_rcpf(1.0f + __expf(-x));
}
__device__ __forceinline__ float tanhf_fast(float x) {
    x = fminf(fmaxf(x, -20.0f), 20.0f);
    float e = __expf(2.0f * x);
    return 1.0f - 2.0f * __builtin_amdgcn_rcpf(e + 1.0f);
}

// fp8 e4m3 shadow copy of x for the message/gather path. Values are encoded
// at 64x scale (exact pow2) so late-layer h (~0.002) stays in e4m3 NORMAL
// range (rel err ~2%) instead of the coarse subnormal band; agg folds the
// 1/64 into the rm weight table. h itself stays bf16 everywhere.
// ONE plane only: agg_l (read) strictly precedes gru_l (overwrite) in stream
// order, so no double-buffer; the plane lives in the old xB slot (gru is now
// in-place on xA), keeping total workspace == the R12-proven footprint.
#define F8SCALE 64.0f
__device__ __forceinline__ uint2 f8enc8(const float* f) {
    int lo = __builtin_amdgcn_cvt_pk_fp8_f32(f[0] * F8SCALE, f[1] * F8SCALE, 0, false);
    lo = __builtin_amdgcn_cvt_pk_fp8_f32(f[2] * F8SCALE, f[3] * F8SCALE, lo, true);
    int hi = __builtin_amdgcn_cvt_pk_fp8_f32(f[4] * F8SCALE, f[5] * F8SCALE, 0, false);
    hi = __builtin_amdgcn_cvt_pk_fp8_f32(f[6] * F8SCALE, f[7] * F8SCALE, hi, true);
    return make_uint2((unsigned)lo, (unsigned)hi);
}
__device__ __forceinline__ void f8acc(float* acc, uint2 p, float w) {
    floatx2 e01 = __builtin_amdgcn_cvt_pk_f32_fp8(p.x, false);
    floatx2 e23 = __builtin_amdgcn_cvt_pk_f32_fp8(p.x, true);
    floatx2 e45 = __builtin_amdgcn_cvt_pk_f32_fp8(p.y, false);
    floatx2 e67 = __builtin_amdgcn_cvt_pk_f32_fp8(p.y, true);
    acc[0] += w * e01[0]; acc[1] += w * e01[1];
    acc[2] += w * e23[0]; acc[3] += w * e23[1];
    acc[4] += w * e45[0]; acc[5] += w * e45[1];
    acc[6] += w * e67[0]; acc[7] += w * e67[1];
}

// ---------------------------------------------------------------- mega-prep:
// place (single-pass fixed-slot edge table) ∥ embed ∥ cprep ∥ wprep ∥ rowmean ∥ accz.
__global__ __launch_bounds__(256) void mega_kernel(
        const int* __restrict__ src, const int* __restrict__ dst,
        const int* __restrict__ et, unsigned* __restrict__ csr,
        int* __restrict__ fill,
        const int* __restrict__ ids, const float* __restrict__ tab, ush_t* __restrict__ x,
        unsigned char* __restrict__ xf8,
        const float* __restrict__ Wih, const float* __restrict__ G,
        const float* __restrict__ Whh, ush_t* __restrict__ WB,
        const float* __restrict__ etab, float* __restrict__ rm,
        float* __restrict__ accz) {
    __shared__ float sW[16 * 128];
    int b = blockIdx.x;
    int t = threadIdx.x;
    int role;          // 0 = place, 1 = embed, 2 = rest
    int idx;
    if (b < 2 * PLACE_BLKS) {
        role = b & 1;
        idx = b >> 1;
    } else {
        int r = b - 2 * PLACE_BLKS;
        if (r < EMB_BLKS - PLACE_BLKS) { role = 1; idx = PLACE_BLKS + r; }
        else { role = 2; idx = r - (EMB_BLKS - PLACE_BLKS); }
    }
    if (role == 0) {
        // ---- single-pass placement: one atomic + one scattered 4B store per edge
        int e = idx * 256 + t;
        if (e < NE) {
            int d  = __builtin_nontemporal_load(dst + e);
            int s  = __builtin_nontemporal_load(src + e);
            int ty = __builtin_nontemporal_load(et + e);
            int pos = atomicAdd(&fill[d], 1);
            if (pos < SLOTS)
                csr[(size_t)d * SLOTS + pos] = (unsigned)s | ((unsigned)(ty - 1) << 17);
        }
        return;
    }
    if (role == 1) {
        // ---- embedding gather -> bf16 row-major + fp8 shadow
        int tid = idx * 256 + t;
        int n = tid >> 4, c = tid & 15;
        if (n >= NPAD) return;
        ushort8_t h;
        uint2 q;
        if (n < NN) {
            int id = __builtin_nontemporal_load(ids + n);
            const fx4* srcp = (const fx4*)(tab + (size_t)(id + 1) * DD + c * 8);
            fx4 v0 = __builtin_nontemporal_load(srcp);
            fx4 v1 = __builtin_nontemporal_load(srcp + 1);
            h[0] = f2bf(v0[0]); h[1] = f2bf(v0[1]); h[2] = f2bf(v0[2]); h[3] = f2bf(v0[3]);
            h[4] = f2bf(v1[0]); h[5] = f2bf(v1[1]); h[6] = f2bf(v1[2]); h[7] = f2bf(v1[3]);
            float fv[8] = {v0[0], v0[1], v0[2], v0[3], v1[0], v1[1], v1[2], v1[3]};
            q = f8enc8(fv);
        } else {
            #pragma unroll
            for (int e2 = 0; e2 < 8; ++e2) h[e2] = 0;
            q = make_uint2(0u, 0u);
        }
        __builtin_nontemporal_store(h, (ushort8_t*)(x + (size_t)n * DD + c * 8));
        *(uint2*)(xf8 + (size_t)n * DD + c * 8) = q;
        return;
    }
    int b2 = idx;
    if (b2 < CPREP_BLKS) {
        // ---- combined weights: C[l,g] = W_l @ Wih_g^T
        int mat = b2 >> 3, rg = b2 & 7;
        int l = mat / 3, g = mat % 3;
        int k0 = rg * 16;
        #pragma unroll
        for (int it = 0; it < 8; ++it) {
            int idx2 = it * 256 + t;
            sW[idx2] = G[(size_t)l * 16384 + (size_t)(k0 + (idx2 >> 7)) * 128 + (idx2 & 127)];
        }
        __syncthreads();
        int col = t & 127, kh = t >> 7;
        float acc[8];
        #pragma unroll
        for (int e2 = 0; e2 < 8; ++e2) acc[e2] = 0.f;
        const float* wr = Wih + (size_t)(g * 128 + col) * 128;
        for (int j = 0; j < 128; ++j) {
            float wv = wr[j];
            #pragma unroll
            for (int e2 = 0; e2 < 8; ++e2) acc[e2] += sW[(kh * 8 + e2) * 128 + j] * wv;
        }
        int M = 3 + l * 3 + g;
        #pragma unroll
        for (int e2 = 0; e2 < 8; ++e2) {
            int k = k0 + kh * 8 + e2;
            int chunk = k >> 5, klo = k & 31;
            int inoff = ((col >> 4) * 4 + (klo >> 3)) * 128 + (col & 15) * 8 + (klo & 7);
            WB[(size_t)(M * 4 + chunk) * 4096 + inoff] = f2bf(acc[e2]);
        }
        return;
    }
    b2 -= CPREP_BLKS;
    if (b2 < WPREP_BLKS) {
        // ---- Whh gates -> WB mats 0..2
        int idx2 = b2 * 256 + t;
        int mat = idx2 >> 14;
        int rem = idx2 & 16383;
        int col = rem & 127, kk = rem >> 7;
        float w = Whh[((size_t)mat * 128 + col) * 128 + kk];
        int chunk = kk >> 5, klo = kk & 31;
        int inoff = ((col >> 4) * 4 + (klo >> 3)) * 128 + (col & 15) * 8 + (klo & 7);
        WB[(size_t)(mat * 4 + chunk) * 4096 + inoff] = f2bf(w);
        return;
    }
    b2 -= WPREP_BLKS;
    if (b2 < 7) {
        // ---- row means of edge-type table (7 blocks)
        int r = b2;
        float v = (t < 128) ? etab[r * DD + t] : 0.f;
        #pragma unroll
        for (int o = 32; o > 0; o >>= 1) v += __shfl_xor(v, o);
        if ((t & 63) == 0) sW[t >> 6] = v;
        __syncthreads();
        if (t == 0) rm[r] = (sW[0] + sW[1]) * (1.0f / DD);
        return;
    }
    // ---- zero pooling accumulators (1 block)
    for (int i = t; i < 64 * 128 + 64; i += 256) accz[i] = 0.f;
}

// ---------------------------------------------------------------- slot-table gather: g = sum rm[et]*x[src]
// fp8 message path: 16 lanes per node, 8-B row loads (half the bytes AND
// half the TA line-segments of the bf16 version). srm folds the 1/64 scale.
__global__ __launch_bounds__(512) void agg_kernel(const unsigned char* __restrict__ xf8,
                                                  const int* __restrict__ fill,
                                                  const unsigned* __restrict__ csr,
                                                  const float* __restrict__ rm,
                                                  ush_t* __restrict__ gH) {
    __shared__ float srm[8];
    int t = threadIdx.x;
    if (t < 7) srm[t] = rm[t] * (1.0f / F8SCALE);
    __syncthreads();
    int grp = t >> 4, c = t & 15;
    int n = blockIdx.x * 32 + grp;
    if (n >= NPAD) return;
    int nout = ((n >> 7) << 14) + ((c >> 2) << 12) + (((n >> 4) & 7) << 9)
             + ((c & 3) << 7) + ((n & 15) << 3);
    if (n >= NN) {
        ushort8_t z;
        #pragma unroll
        for (int k = 0; k < 8; ++k) z[k] = 0;
        *(ushort8_t*)(gH + nout) = z;
        return;
    }
    const unsigned char* xc = xf8 + c * 8;
    const unsigned* cp = csr + (size_t)n * SLOTS;
    int cnt = fill[n];
    if (cnt > SLOTS) cnt = SLOTS;
    float acc[8];
    #pragma unroll
    for (int k = 0; k < 8; ++k) acc[k] = 0.f;
    int e = 0;
    for (; e + 3 < cnt; e += 4) {
        unsigned r0 = cp[e], r1 = cp[e + 1], r2 = cp[e + 2], r3 = cp[e + 3];
        uint2 p0 = *(const uint2*)(xc + (size_t)(r0 & 0x1FFFFu) * DD);
        uint2 p1 = *(const uint2*)(xc + (size_t)(r1 & 0x1FFFFu) * DD);
        uint2 p2 = *(const uint2*)(xc + (size_t)(r2 & 0x1FFFFu) * DD);
        uint2 p3 = *(const uint2*)(xc + (size_t)(r3 & 0x1FFFFu) * DD);
        f8acc(acc, p0, srm[r0 >> 17]);
        f8acc(acc, p1, srm[r1 >> 17]);
        f8acc(acc, p2, srm[r2 >> 17]);
        f8acc(acc, p3, srm[r3 >> 17]);
    }
    for (; e < cnt; ++e) {
        unsigned r0 = cp[e];
        uint2 p0 = *(const uint2*)(xc + (size_t)(r0 & 0x1FFFFu) * DD);
        f8acc(acc, p0, srm[r0 >> 17]);
    }
    ushort8_t oh;
    #pragma unroll
    for (int k = 0; k < 8; ++k) oh[k] = f2bf(acc[k]);
    *(ushort8_t*)(gH + nout) = oh;
}

// ---------------------------------------------------------------- GRU layer kernel (64-row tiles, 8 waves)
// (512,4): the proven equilibrium. IN-PLACE on the x plane: each block reads
// only its own 64 rows (staged to LDS before the barrier) and writes only
// those rows, so xout == xin is race-free; agg_{l+1} is stream-ordered after.
// Also writes the fp8 shadow (next layer's agg input).
__global__ __launch_bounds__(512, 4) void gru_kernel(ush_t* __restrict__ xio,
                                                     const ush_t* __restrict__ gH,
                                                     unsigned char* __restrict__ xf8out,
                                                     const ush_t* __restrict__ WB,
                                                     const float* __restrict__ bih,
                                                     const float* __restrict__ bhh,
                                                     int layer, int is_last,
                                                     const float* __restrict__ gw,
                                                     const float* __restrict__ gb,
                                                     float* __restrict__ accum,
                                                     float* __restrict__ den) {
    __shared__ ush_t sX[64 * 136];
    __shared__ ush_t sG[64 * 128];     // frag-plane chunk, linear
    __shared__ float pl[64];
    int t = threadIdx.x;
    int tb = blockIdx.x;
    int n0 = tb * 64;
    // --- stage x tile (row-major, padded pitch)
    #pragma unroll
    for (int it = 0; it < 2; ++it) {
        int idx = it * 512 + t;          // 1024 chunks of 16B
        int row = idx >> 4, seg = idx & 15;
        ushort8_t v = *(const ushort8_t*)(xio + (size_t)(n0 + row) * DD + seg * 8);
        *(ushort8_t*)(sX + row * 136 + seg * 8) = v;
    }
    // --- stage gH tile: block's data = 4 pieces of 2048 ush at 4096 stride
    {
        size_t gsrc = (size_t)(tb >> 1) * 16384 + (size_t)(tb & 1) * 2048;
        #pragma unroll
        for (int it = 0; it < 2; ++it) {
            int o = (it * 512 + t) * 8;                 // ush offset, 0..8191
            ushort8_t v = *(const ushort8_t*)(gH + gsrc + (o >> 11) * 4096 + (o & 2047));
            *(ushort8_t*)(sG + o) = v;
        }
    }
    __syncthreads();
    // --- MFMA
    int l = t & 63, w = t >> 6;          // w = 0..7: column tile
    int lg = l >> 4, lc = l & 15;
    floatx4 accR[4], accZ[4], accN[4], accI[4];
    #pragma unroll
    for (int i = 0; i < 4; ++i) {
        accR[i] = (floatx4)0.f; accZ[i] = (floatx4)0.f;
        accN[i] = (floatx4)0.f; accI[i] = (floatx4)0.f;
    }
    int boff = ((w * 4 + lg) * 16 + lc) * 8;
    #pragma unroll
    for (int pass = 0; pass < 2; ++pass) {
        int matbase = pass ? (3 + layer * 3) : 0;
        #pragma unroll
        for (int kc = 0; kc < 4; ++kc) {
            short8 aHf[4];
            if (pass == 0) {
                #pragma unroll
                for (int i = 0; i < 4; ++i)
                    aHf[i] = *(const short8*)(sX + (i * 16 + lc) * 136 + kc * 32 + lg * 8);
            } else {
                #pragma unroll
                for (int i = 0; i < 4; ++i)
                    aHf[i] = *(const short8*)(sG + kc * 2048 + i * 512 + lg * 128 + lc * 8);
            }
            #pragma unroll
            for (int m3 = 0; m3 < 3; ++m3) {
                floatx4* accp = (m3 == 0) ? accR : (m3 == 1) ? accZ : (pass ? accI : accN);
                const ush_t* wb = WB + (size_t)((matbase + m3) * 4 + kc) * 4096;
                short8 bH = *(const short8*)(wb + boff);
                #pragma unroll
                for (int i = 0; i < 4; ++i)
                    accp[i] = __builtin_amdgcn_mfma_f32_16x16x32_bf16(aHf[i], bH, accp[i], 0, 0, 0);
            }
        }
    }
    __syncthreads();   // all sX A-frag reads done before overwrite
    // --- gates + blend, in-place into sX
    {
        int col = w * 16 + lc;
        float bIr = bih[col],       bHr = bhh[col];
        float bIz = bih[128 + col], bHz = bhh[128 + col];
        float bIn = bih[256 + col], bHn = bhh[256 + col];
        #pragma unroll
        for (int i = 0; i < 4; ++i)
            #pragma unroll
            for (int r = 0; r < 4; ++r) {
                int row = i * 16 + lg * 4 + r;
                float v = 0.f;
                if (n0 + row < NN) {
                    float rr = sigf(accR[i][r] + bIr + bHr);
                    float zz = sigf(accZ[i][r] + bIz + bHz);
                    float nn = tanhf_fast(accI[i][r] + bIn + rr * (accN[i][r] + bHn));
                    float h = bf2f(sX[row * 136 + col]);
                    v = (1.0f - zz) * nn + zz * h;
                }
                sX[row * 136 + col] = f2bf(v);
            }
    }
    __syncthreads();
    if (!is_last) {
        // --- coalesced row-major write-out: bf16 state (in-place) + fp8 shadow
        #pragma unroll
        for (int it = 0; it < 2; ++it) {
            int idx = it * 512 + t;
            int row = idx >> 4, seg = idx & 15;
            ushort8_t v = *(const ushort8_t*)(sX + row * 136 + seg * 8);
            *(ushort8_t*)(xio + (size_t)(n0 + row) * DD + seg * 8) = v;
            float fv[8];
            #pragma unroll
            for (int j = 0; j < 8; ++j) fv[j] = bf2f(v[j]);
            uint2 q = f8enc8(fv);
            *(uint2*)(xf8out + (size_t)(n0 + row) * DD + seg * 8) = q;
        }
    } else {
        // --- fused global-attention pooling (replicated accumulators)
        int row = t >> 3, q = t & 7;      // 8 threads per row, 16 cols each
        float s = 0.f;
        #pragma unroll
        for (int e = 0; e < 16; ++e)
            s += bf2f(sX[row * 136 + q * 16 + e]) * gw[q * 16 + e];
        s += __shfl_xor(s, 1);
        s += __shfl_xor(s, 2);
        s += __shfl_xor(s, 4);
        if (q == 0)
            pl[row] = (n0 + row < NN) ? __expf(sigf(s + gb[0])) : 0.f;
        __syncthreads();
        int cc = t & 127, qr = t >> 7;    // 4 quarters of 16 rows each
        float acc = 0.f;
        #pragma unroll
        for (int r = 0; r < 16; ++r)
            acc += pl[qr * 16 + r] * bf2f(sX[(qr * 16 + r) * 136 + cc]);
        atomicAdd(&accum[(tb & 63) * 128 + cc], acc);
        if (t < 64) {
            float v = pl[t];
            #pragma unroll
            for (int o = 32; o > 0; o >>= 1) v += __shfl_xor(v, o);
            if (t == 0) atomicAdd(&den[tb & 63], v);
        }
    }
}

__global__ void finalize_kernel(const float* __restrict__ accum, const float* __restrict__ den,
                                float* __restrict__ out) {
    __shared__ float dsum;
    int d = threadIdx.x;   // 128
    float s = 0.f;
    for (int rep = 0; rep < 64; ++rep) s += accum[rep * 128 + d];
    if (d == 0) {
        float ds = 0.f;
        for (int rep = 0; rep < 64; ++rep) ds += den[rep];
        dsum = ds;
    }
    __syncthreads();
    out[d] = s / dsum;
}

// ---------------------------------------------------------------- launch
extern "C" void kernel_launch(void* const* d_in, const int* in_sizes, int n_in,
                              void* d_out, int out_size, void* d_ws, size_t ws_size,
                              hipStream_t stream) {
    const int*   node_ids    = (const int*)d_in[0];
    const int*   edges       = (const int*)d_in[1];
    const int*   edge_types  = (const int*)d_in[2];
    const float* embed_table = (const float*)d_in[3];
    const float* edge_tab    = (const float*)d_in[4];
    const float* ggnn_w      = (const float*)d_in[5];
    const float* Wih         = (const float*)d_in[6];
    const float* Whh         = (const float*)d_in[7];
    const float* bih         = (const float*)d_in[8];
    const float* bhh         = (const float*)d_in[9];
    const float* gate_w      = (const float*)d_in[10];
    const float* gate_b      = (const float*)d_in[11];
    float* out = (float*)d_out;

    const size_t PL = (size_t)NPAD * DD;
    ush_t* wsb  = (ush_t*)d_ws;
    ush_t* xA   = wsb;                      // bf16 state plane (in-place across layers)
    unsigned char* xF8 = (unsigned char*)(xA + PL);   // fp8 shadow plane (old xB slot)
    ush_t* gH   = xA + 2 * PL;              // frag plane (same offset as R12)
    ush_t* WB   = gH + PL;                  // 15 mats * 4 chunks * 4096
    unsigned* csr = (unsigned*)(WB + 15 * 4 * 4096);  // NPAD*SLOTS 4B records
    float* accum = (float*)(csr + (size_t)NPAD * SLOTS);  // 64 * 128
    float* den   = accum + 64 * 128;    // 64
    float* rm    = den + 64;            // 7(+1)
    int*   fill  = (int*)(rm + 8);      // N

    const int* src = edges;
    const int* dst = edges + NE;

    // prep: memset fill, then ONE mega kernel (place ∥ embed ∥ cprep ∥ wprep ∥ rowmean ∥ accz)
    hipMemsetAsync(fill, 0, NN * sizeof(int), stream);
    mega_kernel<<<MEGA_BLKS, 256, 0, stream>>>(src, dst, edge_types, csr, fill,
                                               node_ids, embed_table, xA, xF8,
                                               Wih, ggnn_w, Whh, WB,
                                               edge_tab, rm, accum);

    // 4 layers: standalone high-occupancy gather (fp8) + gru (bf16, in-place)
    for (int layer = 0; layer < 4; ++layer) {
        agg_kernel<<<(NPAD + 31) / 32, 512, 0, stream>>>(xF8, fill, csr, rm, gH);
        gru_kernel<<<NT64, 512, 0, stream>>>(xA, gH, xF8, WB, bih, bhh,
                                             layer, layer == 3 ? 1 : 0,
                                             gate_w, gate_b, accum, den);
    }

    finalize_kernel<<<1, 128, 0, stream>>>(accum, den, out);
}